// Round 5
// baseline (1311.779 us; speedup 1.0000x reference)
//
#include <hip/hip_runtime.h>
#include <hip/hip_bf16.h>
#include <cstddef>

#define N_NODES 10000
#define KTOP 30
#define CAP 2048     // max CSR row length
#define NQ4 (N_NODES / 4)   // 2500 float4 per row
#define NTILE 79     // ceil(10000/128)

typedef _Float16 f16x8 __attribute__((ext_vector_type(8)));
typedef float f32x4 __attribute__((ext_vector_type(4)));

// ---------------- fp16 2-way split helpers ----------------
// split(v): hi = f16(v*256), lo = f16(v*256 - hi). Scale 2^8 keeps values in
// the fp16 normal range; undone by 2^-16 after the hi/lo product GEMM.
__global__ __launch_bounds__(256) void split_rows(const float* __restrict__ src,
                                                  _Float16* __restrict__ hi,
                                                  _Float16* __restrict__ lo,
                                                  int n) {
    int i = blockIdx.x * 256 + threadIdx.x;
    if (i >= n) { return; }
    float v = src[i] * 256.0f;
    _Float16 h = (_Float16)v;
    hi[i] = h;
    lo[i] = (_Float16)(v - (float)h);
}

// W[k][n] (256 x N) -> Wt[n][k] split (so GEMM B-addressing == A-addressing)
__global__ __launch_bounds__(256) void splitWT(const float* __restrict__ W,
                                               _Float16* __restrict__ hi,
                                               _Float16* __restrict__ lo,
                                               int N) {
    int n = blockIdx.x;
    int k = threadIdx.x;
    float v = W[k * N + n] * 256.0f;
    _Float16 h = (_Float16)v;
    hi[n * 256 + k] = h;
    lo[n * 256 + k] = (_Float16)(v - (float)h);
}

// ---------------- row normalize, numpy-pairwise-exact semantics ----------------
__global__ __launch_bounds__(256) void rownorm_np_kernel(const float* __restrict__ h,
                                                         _Float16* __restrict__ hhi,
                                                         _Float16* __restrict__ hlo) {
    __shared__ float row[256];
    __shared__ float denom_sh;
    int r = blockIdx.x;
    int t = threadIdx.x;
    const float* p = h + (size_t)r * 256;
    row[t] = p[t];
    __syncthreads();
    if (t < 16) {
        int half = t >> 3;
        int j = t & 7;
        const float* a = row + half * 128 + j;
        float rr = __fmul_rn(a[0], a[0]);
        #pragma unroll
        for (int i = 1; i < 16; i++) {
            rr = __fadd_rn(rr, __fmul_rn(a[i * 8], a[i * 8]));
        }
        #pragma unroll
        for (int off = 1; off <= 8; off <<= 1) {
            rr = __fadd_rn(rr, __shfl_xor(rr, off, 64));
        }
        if (t == 0) { denom_sh = __fadd_rn(__fsqrt_rn(rr), 1e-8f); }
    }
    __syncthreads();
    float v = __fdiv_rn(row[t], denom_sh);
    float sc = v * 256.0f;                 // exact (power-of-2 scale)
    _Float16 hv = (_Float16)sc;            // RNE to fp16
    float rem = sc - (float)hv;            // exact (Sterbenz-range)
    hhi[(size_t)r * 256 + t] = hv;
    hlo[(size_t)r * 256 + t] = (_Float16)rem;
}

// ---------------- global_load_lds helper ----------------
__device__ __forceinline__ void gload16(const void* g, void* l) {
    __builtin_amdgcn_global_load_lds(
        (const __attribute__((address_space(1))) unsigned int*)g,
        (__attribute__((address_space(3))) unsigned int*)l, 16, 0, 0);
}

// ---------------- S tile GEMM via fp16-split MFMA, double-buffered pipeline ----------------
// Additionally emits per-(row, col-tile) maxes of relu(S) into TM[10000][80]
// (row-part for this block's rows, col-part for the mirrored rows), computed
// with exact fmax trees from acc -> bounds for the top-k pruning pass.
__global__ __launch_bounds__(256) void gemm_s_f16(const _Float16* __restrict__ hi,
                                                  const _Float16* __restrict__ lo,
                                                  float* __restrict__ S,
                                                  float* __restrict__ TM) {
    int rb = blockIdx.y * 128;
    int cb = blockIdx.x * 128;
    if (cb < rb) { return; }
    __shared__ __align__(16) unsigned short Hs[2][16384];  // 2 x 32 KB (A at 0, B at 8192)
    int t = threadIdx.x;
    int w = t >> 6;
    int lane = t & 63;
    int wr = w >> 1, wc = w & 1;          // wave -> 64x64 quadrant
    int lrow = lane & 15, lk = lane >> 4; // mfma A/B fragment mapping
    int lr8 = lane >> 3, ls8 = lane & 7;  // staging: 8 rows x 8 phys slots per 1KB chunk

    int slog = ls8 ^ lr8;                  // logical slot this lane sources
    const char* srcp = (slog < 4) ? (const char*)hi : (const char*)lo;
    int koff = (slog & 3) * 16;            // 16B k-slot within the stage's 64B range
    int cbase = w * 8;

    f32x4 acc[4][4];
    #pragma unroll
    for (int i = 0; i < 4; i++) {
        #pragma unroll
        for (int j = 0; j < 4; j++) {
            f32x4 z = {0.f, 0.f, 0.f, 0.f};
            acc[i][j] = z;
        }
    }

    auto STAGE = [&](int sidx, int b) {
        int kb = sidx * 64;                // byte offset of stage's k-range (32 halves)
        #pragma unroll
        for (int tt = 0; tt < 8; tt++) {
            int c = cbase + tt;            // chunk 0..31
            int rl = ((c & 15) << 3) + lr8;
            int node = ((c >> 4) ? cb : rb) + rl;
            if (node > N_NODES - 1) { node = N_NODES - 1; }
            gload16(srcp + (size_t)node * 512 + kb + koff, &Hs[b][c << 9]);
        }
    };

    STAGE(0, 0);
    #pragma unroll 1
    for (int s = 0; s < 8; s++) {
        int b = s & 1;
        if (s < 7) { STAGE(s + 1, b ^ 1); }
        __builtin_amdgcn_sched_barrier(0);
        if (s < 7) { asm volatile("s_waitcnt vmcnt(8)" ::: "memory"); }
        else       { asm volatile("s_waitcnt vmcnt(0)" ::: "memory"); }
        __builtin_amdgcn_s_barrier();
        __builtin_amdgcn_sched_barrier(0);
        f16x8 ah[4], al[4], bh[4], bl[4];
        #pragma unroll
        for (int i = 0; i < 4; i++) {
            int ar = wr * 64 + i * 16 + lrow;
            int br = wc * 64 + i * 16 + lrow;
            int ra7 = ar & 7, rb7 = br & 7;
            ah[i] = *(const f16x8*)&Hs[b][ar * 64 + ((lk ^ ra7) << 3)];
            al[i] = *(const f16x8*)&Hs[b][ar * 64 + (((lk + 4) ^ ra7) << 3)];
            bh[i] = *(const f16x8*)&Hs[b][8192 + br * 64 + ((lk ^ rb7) << 3)];
            bl[i] = *(const f16x8*)&Hs[b][8192 + br * 64 + (((lk + 4) ^ rb7) << 3)];
        }
        #pragma unroll
        for (int i = 0; i < 4; i++) {
            #pragma unroll
            for (int j = 0; j < 4; j++) {
                acc[i][j] = __builtin_amdgcn_mfma_f32_16x16x32_f16(ah[i], bh[j], acc[i][j], 0, 0, 0);
                acc[i][j] = __builtin_amdgcn_mfma_f32_16x16x32_f16(ah[i], bl[j], acc[i][j], 0, 0, 0);
                acc[i][j] = __builtin_amdgcn_mfma_f32_16x16x32_f16(al[i], bh[j], acc[i][j], 0, 0, 0);
            }
        }
        __builtin_amdgcn_sched_barrier(0);
        __builtin_amdgcn_s_barrier();
    }

    const float inv = 1.0f / 65536.0f;  // undo 2^8 * 2^8 operand scaling (exact)

    // ---- per-(row, tile) maxes: Hs is dead (post trailing barrier) -> scratch.
    {
        float* red = (float*)Hs;       // [0..255] rowpart [wc][128]; [256..511] colpart [wr][128]
        float rm[4][4];
        #pragma unroll
        for (int i = 0; i < 4; i++) {
            #pragma unroll
            for (int q = 0; q < 4; q++) {
                float m = fmaxf(fmaxf(acc[i][0][q], acc[i][1][q]),
                                fmaxf(acc[i][2][q], acc[i][3][q]));
                #pragma unroll
                for (int off = 1; off <= 8; off <<= 1) { m = fmaxf(m, __shfl_xor(m, off, 64)); }
                rm[i][q] = m;
            }
        }
        if ((lane & 15) == 0) {
            #pragma unroll
            for (int i = 0; i < 4; i++) {
                #pragma unroll
                for (int q = 0; q < 4; q++) {
                    red[wc * 128 + wr * 64 + i * 16 + lk * 4 + q] = rm[i][q];
                }
            }
        }
        float cm[4];
        #pragma unroll
        for (int j = 0; j < 4; j++) {
            float m = acc[0][j][0];
            #pragma unroll
            for (int i = 0; i < 4; i++) {
                #pragma unroll
                for (int q = 0; q < 4; q++) {
                    if (i + q) { m = fmaxf(m, acc[i][j][q]); }
                }
            }
            m = fmaxf(m, __shfl_xor(m, 16, 64));
            m = fmaxf(m, __shfl_xor(m, 32, 64));
            cm[j] = m;
        }
        if (lk == 0) {
            #pragma unroll
            for (int j = 0; j < 4; j++) {
                red[256 + wr * 128 + wc * 64 + j * 16 + lrow] = cm[j];
            }
        }
        __syncthreads();
        if (t < 128) {
            float rmx = fmaxf(red[t], red[128 + t]) * inv;
            int gr = rb + t;
            if (gr < N_NODES) { TM[(size_t)gr * 80 + (cb >> 7)] = fmaxf(rmx, 0.f); }
            float cmx = fmaxf(red[256 + t], red[384 + t]) * inv;
            int gc = cb + t;
            if (gc < N_NODES) { TM[(size_t)gc * 80 + (rb >> 7)] = fmaxf(cmx, 0.f); }
        }
    }

    // epilogue: C/D frag layout col = lane&15, row = (lane>>4)*4 + reg.
    #pragma unroll
    for (int i = 0; i < 4; i++) {
        int rrb = rb + wr * 64 + i * 16 + lk * 4;
        #pragma unroll
        for (int j = 0; j < 4; j++) {
            int cc = cb + wc * 64 + j * 16 + lrow;
            if (cc >= N_NODES) { continue; }
            #pragma unroll
            for (int q = 0; q < 4; q++) {
                int rr = rrb + q;
                if (rr >= N_NODES) { continue; }
                float v = fmaxf(acc[i][j][q] * inv, 0.f);
                S[(size_t)rr * N_NODES + cc] = v;
                S[(size_t)cc * N_NODES + rr] = v;  // mirror (bit-identical dot)
            }
        }
    }
}

// ---------------- generic 128-tile GEMM via fp16-split MFMA ----------------
template<int MODE>
__global__ __launch_bounds__(256) void gemm_mlp(const _Float16* __restrict__ ahi,
                                                const _Float16* __restrict__ alo,
                                                const _Float16* __restrict__ bhi,
                                                const _Float16* __restrict__ blo,
                                                _Float16* __restrict__ chi,
                                                _Float16* __restrict__ clo,
                                                float* __restrict__ cf,
                                                const float* __restrict__ bias,
                                                int on) {
    int rb = blockIdx.y * 128;
    int cb = blockIdx.x * 128;
    __shared__ __align__(16) unsigned short Hs[32768];  // 64 KB
    int t = threadIdx.x;
    int w = t >> 6;
    int lane = t & 63;
    int wr = w >> 1, wc = w & 1;
    int lrow = lane & 15, lk = lane >> 4;
    int lr8 = lane >> 3, ls8 = lane & 7;
    int koffb = ((ls8 ^ lr8) << 4);

    f32x4 acc[4][4];
    #pragma unroll
    for (int i = 0; i < 4; i++) {
        #pragma unroll
        for (int j = 0; j < 4; j++) {
            f32x4 z = {0.f, 0.f, 0.f, 0.f};
            acc[i][j] = z;
        }
    }

    const char* ahp = (const char*)ahi;
    const char* alp = (const char*)alo;
    const char* bhp = (const char*)bhi;
    const char* blp = (const char*)blo;

    #pragma unroll 1
    for (int ks = 0; ks < 4; ks++) {
        int k0b = ks * 128;
        #pragma unroll
        for (int tt = 0; tt < 4; tt++) {
            int c = w * 4 + tt;
            int rowloc = c * 8 + lr8;
            int na = rb + rowloc; if (na > N_NODES - 1) { na = N_NODES - 1; }
            int nb = cb + rowloc;              // Wt rows always valid
            size_t offA = (size_t)na * 512 + k0b + koffb;
            size_t offB = (size_t)nb * 512 + k0b + koffb;
            gload16(ahp + offA, &Hs[0     + c * 512]);
            gload16(alp + offA, &Hs[8192  + c * 512]);
            gload16(bhp + offB, &Hs[16384 + c * 512]);
            gload16(blp + offB, &Hs[24576 + c * 512]);
        }
        __builtin_amdgcn_s_waitcnt(0);
        __syncthreads();
        #pragma unroll 1
        for (int kk = 0; kk < 2; kk++) {
            f16x8 ah[4], al[4], bh[4], bl[4];
            #pragma unroll
            for (int i = 0; i < 4; i++) {
                int ar = wr * 64 + i * 16 + lrow;
                int br = wc * 64 + i * 16 + lrow;
                int ps = ((kk * 4 + lk) ^ (lrow & 7)) * 8;
                ah[i] = *(const f16x8*)&Hs[0     + ar * 64 + ps];
                al[i] = *(const f16x8*)&Hs[8192  + ar * 64 + ps];
                bh[i] = *(const f16x8*)&Hs[16384 + br * 64 + ps];
                bl[i] = *(const f16x8*)&Hs[24576 + br * 64 + ps];
            }
            #pragma unroll
            for (int i = 0; i < 4; i++) {
                #pragma unroll
                for (int j = 0; j < 4; j++) {
                    acc[i][j] = __builtin_amdgcn_mfma_f32_16x16x32_f16(ah[i], bh[j], acc[i][j], 0, 0, 0);
                    acc[i][j] = __builtin_amdgcn_mfma_f32_16x16x32_f16(ah[i], bl[j], acc[i][j], 0, 0, 0);
                    acc[i][j] = __builtin_amdgcn_mfma_f32_16x16x32_f16(al[i], bh[j], acc[i][j], 0, 0, 0);
                }
            }
        }
        __syncthreads();
    }

    const float inv = 1.0f / 65536.0f;
    #pragma unroll
    for (int i = 0; i < 4; i++) {
        int rrb = rb + wr * 64 + i * 16 + lk * 4;
        #pragma unroll
        for (int j = 0; j < 4; j++) {
            int cc = cb + wc * 64 + j * 16 + lrow;
            if (cc >= on && MODE == 0) { continue; }
            #pragma unroll
            for (int q = 0; q < 4; q++) {
                int rr = rrb + q;
                if (rr >= N_NODES) { continue; }
                if (MODE == 1) {
                    float sv = fmaxf(acc[i][j][q], 0.f) * (1.0f / 256.0f);
                    _Float16 hv = (_Float16)sv;
                    chi[(size_t)rr * 256 + cc] = hv;
                    clo[(size_t)rr * 256 + cc] = (_Float16)(sv - (float)hv);
                } else {
                    float v = acc[i][j][q] * inv;
                    if (bias != nullptr) { v += bias[cc]; }
                    cf[(size_t)rr * on + cc] = v;
                }
            }
        }
    }
}

// ---------------- bound-pruned exact top-30, ties -> HIGHEST index ----------------
// One wave per row. cur top-30 sorted (value desc, idx desc), lane-distributed
// (lane k = k-th best). Tiles visited in tile-max desc order; stop when best
// remaining tile-max < cur[29].v (process on >=, preserving index-tie exactness).
// Fuses degree accumulation (deg pre-zeroed). Does NOT zero S.
__global__ __launch_bounds__(64) void topk_bound_kernel(const float* __restrict__ S,
                                                        const float* __restrict__ TM,
                                                        float* __restrict__ tv,
                                                        int* __restrict__ ti,
                                                        float* __restrict__ deg) {
    int r = blockIdx.x;
    int lane = threadIdx.x;
    const float* trow = TM + (size_t)r * 80;
    const float* row = S + (size_t)r * N_NODES;
    float m0 = trow[lane];                                   // tiles 0..63 (<79 always)
    float m1 = (lane + 64 < NTILE) ? trow[lane + 64] : -3.f; // tiles 64..78
    float cv = -1.f; int ci = -1;                            // sorted list (lanes 0..29)
    float thrv = -1.f; int thri = -1;                        // = cur[29]

    while (true) {
        // best unprocessed tile
        float bm = m0; int bt = lane;
        if (m1 > bm) { bm = m1; bt = lane + 64; }
        #pragma unroll
        for (int off = 32; off > 0; off >>= 1) {
            float ov = __shfl_xor(bm, off, 64);
            int ot = __shfl_xor(bt, off, 64);
            if (ov > bm || (ov == bm && ot > bt)) { bm = ov; bt = ot; }
        }
        if (bm < thrv) { break; }
        if (bt == lane) { m0 = -3.f; }
        if (bt == lane + 64) { m1 = -3.f; }

        int c0 = bt * 128 + lane;
        int c1 = c0 + 64;
        float x0 = (c0 < N_NODES) ? row[c0] : -2.f;
        float x1 = (c1 < N_NODES) ? row[c1] : -2.f;

        while (true) {
            // best candidate outranking cur[29] (lex: value desc, idx desc)
            float nv = -3.f; int nc = -1;
            if ((x0 > thrv) || (x0 == thrv && c0 > thri)) { nv = x0; nc = c0; }
            if (((x1 > thrv) || (x1 == thrv && c1 > thri)) &&
                (x1 > nv || (x1 == nv && c1 > nc))) { nv = x1; nc = c1; }
            #pragma unroll
            for (int off = 32; off > 0; off >>= 1) {
                float ov = __shfl_xor(nv, off, 64);
                int oc = __shfl_xor(nc, off, 64);
                if (ov > nv || (ov == nv && oc > nc)) { nv = ov; nc = oc; }
            }
            if (nc < 0) { break; }
            // insertion: pos = #cur entries outranking cand (contiguous prefix)
            int outrank = ((cv > nv) || (cv == nv && ci > nc)) ? 1 : 0;
            unsigned long long mk = __ballot(outrank);
            int pos = __builtin_popcountll(mk);
            float pv = __shfl_up(cv, 1, 64);
            int pi = __shfl_up(ci, 1, 64);
            if (lane == pos) { cv = nv; ci = nc; }
            else if (lane > pos && lane < 30) { cv = pv; ci = pi; }
            if (c0 == nc) { x0 = -2.f; }
            if (c1 == nc) { x1 = -2.f; }
            thrv = __shfl(cv, 29, 64);
            thri = __shfl(ci, 29, 64);
        }
    }

    if (lane < 30) {
        tv[r * KTOP + lane] = cv;
        ti[r * KTOP + lane] = ci;
        atomicAdd(deg + ci, 0.5f * cv);
    }
    float s = (lane < 30) ? cv : 0.f;
    #pragma unroll
    for (int off = 32; off > 0; off >>= 1) { s += __shfl_xor(s, off, 64); }
    if (lane == 0) { atomicAdd(deg + r, 0.5f * s); }
}

// ---------------- zero fill ----------------
__global__ __launch_bounds__(256) void zero_fill(float4* __restrict__ p, unsigned int n4) {
    unsigned int i = blockIdx.x * 256u + threadIdx.x;
    unsigned int stride = gridDim.x * 256u;
    float4 z = {0.f, 0.f, 0.f, 0.f};
    for (; i < n4; i += stride) { p[i] = z; }
}

__global__ __launch_bounds__(256) void dis_kernel(const float* __restrict__ deg,
                                                  float* __restrict__ dis) {
    int i = blockIdx.x * 256 + threadIdx.x;
    if (i < N_NODES) {
        float d = deg[i];
        dis[i] = d > 0.f ? 1.f / sqrtf(fmaxf(d, 1e-8f)) : 0.f;
    }
}

// ---------------- CSR build (+ optional fused dense Adj scatter) ----------------
template<int WRITE_ADJ>
__global__ __launch_bounds__(256) void csr_adj(const float* __restrict__ tv,
                                               const int* __restrict__ ti,
                                               const float* __restrict__ dis,
                                               int* __restrict__ cnt,
                                               int* __restrict__ nbr,
                                               float* __restrict__ wgt,
                                               float* __restrict__ Adj) {
    int e = blockIdx.x * 256 + threadIdx.x;
    if (e >= N_NODES * KTOP) { return; }
    int i = e / KTOP;
    int j = ti[e];
    float v = tv[e];
    float vrev = 0.f;
    bool mutual = false;
    const int* tj = ti + (size_t)j * KTOP;
    const float* tvj = tv + (size_t)j * KTOP;
    for (int k = 0; k < KTOP; k++) {
        if (tj[k] == i) { vrev = tvj[k]; mutual = true; }
    }
    float w = 0.5f * (v + vrev) * dis[i] * dis[j];
    int p = atomicAdd(cnt + i, 1);
    if (p < CAP) {
        nbr[(size_t)i * CAP + p] = j;
        wgt[(size_t)i * CAP + p] = w;
    }
    if (!mutual) {
        int p2 = atomicAdd(cnt + j, 1);
        if (p2 < CAP) {
            nbr[(size_t)j * CAP + p2] = i;
            wgt[(size_t)j * CAP + p2] = w;
        }
    }
    if (WRITE_ADJ) {
        Adj[(size_t)i * N_NODES + j] = w;
        Adj[(size_t)j * N_NODES + i] = w;
    }
}

// ---------------- Adj scatter (fallback path only) ----------------
__global__ __launch_bounds__(256) void adj_scatter(const float* __restrict__ tv,
                                                   const int* __restrict__ ti,
                                                   const float* __restrict__ dis,
                                                   float* __restrict__ Adj) {
    int e = blockIdx.x * 256 + threadIdx.x;
    if (e >= N_NODES * KTOP) { return; }
    int i = e / KTOP;
    int j = ti[e];
    float v = tv[e];
    float vrev = 0.f;
    const int* tj = ti + (size_t)j * KTOP;
    const float* tvj = tv + (size_t)j * KTOP;
    for (int k = 0; k < KTOP; k++) {
        if (tj[k] == i) { vrev = tvj[k]; }
    }
    float w = 0.5f * (v + vrev) * dis[i] * dis[j];
    Adj[(size_t)i * N_NODES + j] = w;
    Adj[(size_t)j * N_NODES + i] = w;
}

// ---------------- gather SpMM, 128 channels, relu fused (4x ILP) ----------------
__global__ __launch_bounds__(256) void gather128(const int* __restrict__ cnt,
                                                 const int* __restrict__ nbr,
                                                 const float* __restrict__ wgt,
                                                 const float* __restrict__ T,
                                                 float* __restrict__ Y) {
    int node = blockIdx.x * 2 + (threadIdx.x >> 7);
    int c = threadIdx.x & 127;
    if (node >= N_NODES) { return; }
    int n = cnt[node];
    if (n > CAP) { n = CAP; }
    const int* nb = nbr + (size_t)node * CAP;
    const float* wg = wgt + (size_t)node * CAP;
    float a0 = 0.f, a1 = 0.f, a2 = 0.f, a3 = 0.f;
    int k = 0;
    for (; k + 4 <= n; k += 4) {
        int4 j = *(const int4*)(nb + k);
        float4 w = *(const float4*)(wg + k);
        float t0 = T[(size_t)j.x * 128 + c];
        float t1 = T[(size_t)j.y * 128 + c];
        float t2 = T[(size_t)j.z * 128 + c];
        float t3 = T[(size_t)j.w * 128 + c];
        a0 = fmaf(w.x, t0, a0);
        a1 = fmaf(w.y, t1, a1);
        a2 = fmaf(w.z, t2, a2);
        a3 = fmaf(w.w, t3, a3);
    }
    for (; k < n; k++) { a0 = fmaf(wg[k], T[(size_t)nb[k] * 128 + c], a0); }
    float acc = (a0 + a1) + (a2 + a3);
    Y[(size_t)node * 128 + c] = fmaxf(acc, 0.f);
}

// ---------------- y1[M,128] @ Wg2[128,16] + bg2 -> t2[M,16] ----------------
__global__ __launch_bounds__(256) void gemm16(const float* __restrict__ y1,
                                              const float* __restrict__ Wg2,
                                              const float* __restrict__ bg2,
                                              float* __restrict__ out) {
    __shared__ float Ws[2048];
    __shared__ float Ys[16 * 132];
    int t = threadIdx.x;
    int n0 = blockIdx.x * 16;
    for (int i = t; i < 2048; i += 256) {
        Ws[i] = Wg2[i];
        int rr = i >> 7, cc = i & 127;
        int node = n0 + rr;
        if (node > N_NODES - 1) { node = N_NODES - 1; }
        Ys[rr * 132 + cc] = y1[(size_t)node * 128 + cc];
    }
    __syncthreads();
    int nn = t >> 4;
    int c = t & 15;
    int node = n0 + nn;
    if (node >= N_NODES) { return; }
    const float* yr = Ys + nn * 132;
    float acc = 0.f;
    #pragma unroll 4
    for (int k = 0; k < 128; k++) {
        acc = fmaf(yr[k], Ws[k * 16 + c], acc);
    }
    out[(size_t)node * 16 + c] = acc + bg2[c];
}

// ---------------- gather SpMM, 16 channels (4x ILP) ----------------
__global__ __launch_bounds__(256) void gather16(const int* __restrict__ cnt,
                                                const int* __restrict__ nbr,
                                                const float* __restrict__ wgt,
                                                const float* __restrict__ T,
                                                float* __restrict__ Y) {
    int node = blockIdx.x * 16 + (threadIdx.x >> 4);
    int c = threadIdx.x & 15;
    if (node >= N_NODES) { return; }
    int n = cnt[node];
    if (n > CAP) { n = CAP; }
    const int* nb = nbr + (size_t)node * CAP;
    const float* wg = wgt + (size_t)node * CAP;
    float a0 = 0.f, a1 = 0.f, a2 = 0.f, a3 = 0.f;
    int k = 0;
    for (; k + 4 <= n; k += 4) {
        int4 j = *(const int4*)(nb + k);
        float4 w = *(const float4*)(wg + k);
        float t0 = T[(size_t)j.x * 16 + c];
        float t1 = T[(size_t)j.y * 16 + c];
        float t2 = T[(size_t)j.z * 16 + c];
        float t3 = T[(size_t)j.w * 16 + c];
        a0 = fmaf(w.x, t0, a0);
        a1 = fmaf(w.y, t1, a1);
        a2 = fmaf(w.z, t2, a2);
        a3 = fmaf(w.w, t3, a3);
    }
    for (; k < n; k++) { a0 = fmaf(wg[k], T[(size_t)nb[k] * 16 + c], a0); }
    Y[(size_t)node * 16 + c] = (a0 + a1) + (a2 + a3);
}

extern "C" void kernel_launch(void* const* d_in, const int* in_sizes, int n_in,
                              void* d_out, int out_size, void* d_ws, size_t ws_size,
                              hipStream_t stream) {
    const float* features = (const float*)d_in[0];
    const float* x   = (const float*)d_in[1];
    const float* W1  = (const float*)d_in[2];
    const float* W2  = (const float*)d_in[3];
    const float* Wg1 = (const float*)d_in[4];
    const float* bg1 = (const float*)d_in[5];
    const float* Wg2 = (const float*)d_in[6];
    const float* bg2 = (const float*)d_in[7];

    float* ws = (float*)d_ws;
    // region A [0, 2.56M) floats: fsp -> hbuf -> tmax -> xsp
    // region B [2.56M, 5.12M) floats: h1sp -> Hhi/Hlo -> t1 | y1
    float* hbuf = ws;
    float* tmax = ws;                          // 800,000 f (10000 x 80), over dead hbuf
    float* tv   = ws + 5120000;               // 300,000 f
    int*   ti   = (int*)(ws + 5420000);       // 300,000 i
    float* deg  = ws + 5720000;               // 10,000 f
    float* dis  = ws + 5730000;               // 10,000 f
    float* t2   = ws + 5740000;               // 160,000 f (W-splits live here early)
    int*   cnt  = (int*)(ws + 5900000);       // 10,000 i
    float* t1   = ws + 2560000;               // Hhi region, after gemm_s dead
    float* y1   = ws + 3840000;               // Hlo region, after gemm_s dead

    _Float16* fsphi = (_Float16*)ws;
    _Float16* fsplo = fsphi + 2560000;
    _Float16* xsphi = (_Float16*)ws;                    // after tmax dead (post topk)
    _Float16* xsplo = xsphi + 2560000;
    _Float16* h1hi = (_Float16*)(ws + 2560000);
    _Float16* h1lo = h1hi + 2560000;
    _Float16* Hhi  = (_Float16*)(ws + 2560000);
    _Float16* Hlo  = Hhi + 2560000;
    _Float16* W1thi = (_Float16*)(ws + 5740000);        // 65,536 halves each
    _Float16* W1tlo = W1thi + 65536;
    _Float16* W2thi = W1thi + 131072;
    _Float16* W2tlo = W1thi + 196608;
    _Float16* Wg1thi = (_Float16*)(ws + 5740000);       // reuse after MLP chain (128x256)
    _Float16* Wg1tlo = Wg1thi + 32768;

    float* out_f = (float*)d_out;             // 160,000 f32
    float* Adj   = out_f + 160000;            // 1e8 f32 = 400 MB
    float* Sbuf  = Adj;                       // S until topk

    // CSR placement: workspace if it fits, else alias Adj (zero+scatter at end)
    size_t csr_off = 5910000;                                  // floats
    size_t csr_need = (csr_off + (size_t)N_NODES * CAP * 2) * sizeof(float);
    bool csr_in_ws = ws_size >= csr_need;
    int*   nbr = csr_in_ws ? (int*)(ws + csr_off) : (int*)Adj;
    float* wgt = csr_in_ws ? (float*)(ws + csr_off + (size_t)N_NODES * CAP)
                           : (float*)(Adj + (size_t)N_NODES * CAP);

    // ---- MLP chain via fp16-split MFMA ----
    split_rows<<<dim3(10000), dim3(256), 0, stream>>>(features, fsphi, fsplo, 2560000);
    splitWT<<<dim3(256), dim3(256), 0, stream>>>(W1, W1thi, W1tlo, 256);
    splitWT<<<dim3(256), dim3(256), 0, stream>>>(W2, W2thi, W2tlo, 256);
    gemm_mlp<1><<<dim3(2, 79), dim3(256), 0, stream>>>(
        fsphi, fsplo, W1thi, W1tlo, h1hi, h1lo, (float*)nullptr, (const float*)nullptr, 256);
    gemm_mlp<0><<<dim3(2, 79), dim3(256), 0, stream>>>(
        h1hi, h1lo, W2thi, W2tlo, (_Float16*)nullptr, (_Float16*)nullptr, hbuf,
        (const float*)nullptr, 256);
    rownorm_np_kernel<<<dim3(N_NODES), dim3(256), 0, stream>>>(hbuf, Hhi, Hlo);

    // ---- Wg1 split (W1t/W2t dead) ----
    splitWT<<<dim3(128), dim3(256), 0, stream>>>(Wg1, Wg1thi, Wg1tlo, 128);

    // ---- S (triangle + mirror) + tile maxes; bound-pruned exact top-30 + degrees ----
    gemm_s_f16<<<dim3(79, 79), dim3(256), 0, stream>>>(Hhi, Hlo, Sbuf, tmax);
    hipMemsetAsync(deg, 0, N_NODES * sizeof(float), stream);
    topk_bound_kernel<<<dim3(N_NODES), dim3(64), 0, stream>>>(Sbuf, tmax, tv, ti, deg);

    // ---- Adj zero (S dead) when CSR lives in ws ----
    if (csr_in_ws) {
        zero_fill<<<dim3(2048), dim3(256), 0, stream>>>(
            (float4*)Adj, (unsigned int)((size_t)N_NODES * N_NODES / 4));
    }

    // ---- x split (tmax dead) + GCN layer-1 GEMM ----
    split_rows<<<dim3(10000), dim3(256), 0, stream>>>(x, xsphi, xsplo, 2560000);
    gemm_mlp<0><<<dim3(1, 79), dim3(256), 0, stream>>>(
        xsphi, xsplo, Wg1thi, Wg1tlo, (_Float16*)nullptr, (_Float16*)nullptr, t1, bg1, 128);

    dis_kernel<<<dim3((N_NODES + 255) / 256), dim3(256), 0, stream>>>(deg, dis);

    // ---- CSR build (+ fused Adj scatter when CSR lives in ws) ----
    hipMemsetAsync(cnt, 0, N_NODES * sizeof(int), stream);
    int eblocks = (N_NODES * KTOP + 255) / 256;
    if (csr_in_ws) {
        csr_adj<1><<<dim3(eblocks), dim3(256), 0, stream>>>(tv, ti, dis, cnt, nbr, wgt, Adj);
    } else {
        csr_adj<0><<<dim3(eblocks), dim3(256), 0, stream>>>(tv, ti, dis, cnt, nbr, wgt, Adj);
    }

    // ---- GCN layers via gather SpMM ----
    gather128<<<dim3(N_NODES / 2), dim3(256), 0, stream>>>(cnt, nbr, wgt, t1, y1);
    gemm16<<<dim3(625), dim3(256), 0, stream>>>(y1, Wg2, bg2, t2);
    gather16<<<dim3((N_NODES + 15) / 16), dim3(256), 0, stream>>>(cnt, nbr, wgt, t2, out_f);

    // ---- fallback: CSR aliased Adj -> zero full Adj and scatter dense ----
    if (!csr_in_ws) {
        zero_fill<<<dim3(2048), dim3(256), 0, stream>>>(
            (float4*)Adj, (unsigned int)((size_t)N_NODES * N_NODES / 4));
        adj_scatter<<<dim3(eblocks), dim3(256), 0, stream>>>(tv, ti, dis, Adj);
    }
}

// Round 6
// 1114.337 us; speedup vs baseline: 1.1772x; 1.1772x over previous
//
#include <hip/hip_runtime.h>
#include <hip/hip_bf16.h>
#include <cstddef>

#define N_NODES 10000
#define KTOP 30
#define CAP 2048     // max CSR row length
#define CANDCAP 512
#define NQ4 (N_NODES / 4)   // 2500 float4 per row
#define NTILE 79     // ceil(10000/128)

typedef _Float16 f16x8 __attribute__((ext_vector_type(8)));
typedef float f32x4 __attribute__((ext_vector_type(4)));

// ---------------- fp16 2-way split helpers ----------------
// split(v): hi = f16(v*256), lo = f16(v*256 - hi). Scale 2^8 keeps values in
// the fp16 normal range; undone by 2^-16 after the hi/lo product GEMM.
__global__ __launch_bounds__(256) void split_rows(const float* __restrict__ src,
                                                  _Float16* __restrict__ hi,
                                                  _Float16* __restrict__ lo,
                                                  int n) {
    int i = blockIdx.x * 256 + threadIdx.x;
    if (i >= n) { return; }
    float v = src[i] * 256.0f;
    _Float16 h = (_Float16)v;
    hi[i] = h;
    lo[i] = (_Float16)(v - (float)h);
}

// W[k][n] (256 x N) -> Wt[n][k] split (so GEMM B-addressing == A-addressing)
__global__ __launch_bounds__(256) void splitWT(const float* __restrict__ W,
                                               _Float16* __restrict__ hi,
                                               _Float16* __restrict__ lo,
                                               int N) {
    int n = blockIdx.x;
    int k = threadIdx.x;
    float v = W[k * N + n] * 256.0f;
    _Float16 h = (_Float16)v;
    hi[n * 256 + k] = h;
    lo[n * 256 + k] = (_Float16)(v - (float)h);
}

// ---------------- row normalize, numpy-pairwise-exact semantics ----------------
__global__ __launch_bounds__(256) void rownorm_np_kernel(const float* __restrict__ h,
                                                         _Float16* __restrict__ hhi,
                                                         _Float16* __restrict__ hlo) {
    __shared__ float row[256];
    __shared__ float denom_sh;
    int r = blockIdx.x;
    int t = threadIdx.x;
    const float* p = h + (size_t)r * 256;
    row[t] = p[t];
    __syncthreads();
    if (t < 16) {
        int half = t >> 3;
        int j = t & 7;
        const float* a = row + half * 128 + j;
        float rr = __fmul_rn(a[0], a[0]);
        #pragma unroll
        for (int i = 1; i < 16; i++) {
            rr = __fadd_rn(rr, __fmul_rn(a[i * 8], a[i * 8]));
        }
        #pragma unroll
        for (int off = 1; off <= 8; off <<= 1) {
            rr = __fadd_rn(rr, __shfl_xor(rr, off, 64));
        }
        if (t == 0) { denom_sh = __fadd_rn(__fsqrt_rn(rr), 1e-8f); }
    }
    __syncthreads();
    float v = __fdiv_rn(row[t], denom_sh);
    float sc = v * 256.0f;                 // exact (power-of-2 scale)
    _Float16 hv = (_Float16)sc;            // RNE to fp16
    float rem = sc - (float)hv;            // exact (Sterbenz-range)
    hhi[(size_t)r * 256 + t] = hv;
    hlo[(size_t)r * 256 + t] = (_Float16)rem;
}

// ---------------- global_load_lds helper ----------------
__device__ __forceinline__ void gload16(const void* g, void* l) {
    __builtin_amdgcn_global_load_lds(
        (const __attribute__((address_space(1))) unsigned int*)g,
        (__attribute__((address_space(3))) unsigned int*)l, 16, 0, 0);
}

// ---------------- S tile GEMM via fp16-split MFMA, double-buffered pipeline ----------------
// Additionally emits per-(row, col-tile) maxes of relu(S) into TM[10000][80].
// Boundary tiles may be INFLATED by phantom (clamped) columns — safe: TM is an
// upper bound; topk guards with ncand<KTOP -> fallback.
__global__ __launch_bounds__(256) void gemm_s_f16(const _Float16* __restrict__ hi,
                                                  const _Float16* __restrict__ lo,
                                                  float* __restrict__ S,
                                                  float* __restrict__ TM) {
    int rb = blockIdx.y * 128;
    int cb = blockIdx.x * 128;
    if (cb < rb) { return; }
    __shared__ __align__(16) unsigned short Hs[2][16384];  // 2 x 32 KB (A at 0, B at 8192)
    int t = threadIdx.x;
    int w = t >> 6;
    int lane = t & 63;
    int wr = w >> 1, wc = w & 1;          // wave -> 64x64 quadrant
    int lrow = lane & 15, lk = lane >> 4; // mfma A/B fragment mapping
    int lr8 = lane >> 3, ls8 = lane & 7;  // staging: 8 rows x 8 phys slots per 1KB chunk

    int slog = ls8 ^ lr8;                  // logical slot this lane sources
    const char* srcp = (slog < 4) ? (const char*)hi : (const char*)lo;
    int koff = (slog & 3) * 16;            // 16B k-slot within the stage's 64B range
    int cbase = w * 8;

    f32x4 acc[4][4];
    #pragma unroll
    for (int i = 0; i < 4; i++) {
        #pragma unroll
        for (int j = 0; j < 4; j++) {
            f32x4 z = {0.f, 0.f, 0.f, 0.f};
            acc[i][j] = z;
        }
    }

    auto STAGE = [&](int sidx, int b) {
        int kb = sidx * 64;                // byte offset of stage's k-range (32 halves)
        #pragma unroll
        for (int tt = 0; tt < 8; tt++) {
            int c = cbase + tt;            // chunk 0..31
            int rl = ((c & 15) << 3) + lr8;
            int node = ((c >> 4) ? cb : rb) + rl;
            if (node > N_NODES - 1) { node = N_NODES - 1; }
            gload16(srcp + (size_t)node * 512 + kb + koff, &Hs[b][c << 9]);
        }
    };

    STAGE(0, 0);
    #pragma unroll 1
    for (int s = 0; s < 8; s++) {
        int b = s & 1;
        if (s < 7) { STAGE(s + 1, b ^ 1); }
        __builtin_amdgcn_sched_barrier(0);
        if (s < 7) { asm volatile("s_waitcnt vmcnt(8)" ::: "memory"); }
        else       { asm volatile("s_waitcnt vmcnt(0)" ::: "memory"); }
        __builtin_amdgcn_s_barrier();
        __builtin_amdgcn_sched_barrier(0);
        f16x8 ah[4], al[4], bh[4], bl[4];
        #pragma unroll
        for (int i = 0; i < 4; i++) {
            int ar = wr * 64 + i * 16 + lrow;
            int br = wc * 64 + i * 16 + lrow;
            int ra7 = ar & 7, rb7 = br & 7;
            ah[i] = *(const f16x8*)&Hs[b][ar * 64 + ((lk ^ ra7) << 3)];
            al[i] = *(const f16x8*)&Hs[b][ar * 64 + (((lk + 4) ^ ra7) << 3)];
            bh[i] = *(const f16x8*)&Hs[b][8192 + br * 64 + ((lk ^ rb7) << 3)];
            bl[i] = *(const f16x8*)&Hs[b][8192 + br * 64 + (((lk + 4) ^ rb7) << 3)];
        }
        #pragma unroll
        for (int i = 0; i < 4; i++) {
            #pragma unroll
            for (int j = 0; j < 4; j++) {
                acc[i][j] = __builtin_amdgcn_mfma_f32_16x16x32_f16(ah[i], bh[j], acc[i][j], 0, 0, 0);
                acc[i][j] = __builtin_amdgcn_mfma_f32_16x16x32_f16(ah[i], bl[j], acc[i][j], 0, 0, 0);
                acc[i][j] = __builtin_amdgcn_mfma_f32_16x16x32_f16(al[i], bh[j], acc[i][j], 0, 0, 0);
            }
        }
        __builtin_amdgcn_sched_barrier(0);
        __builtin_amdgcn_s_barrier();
    }

    const float inv = 1.0f / 65536.0f;  // undo 2^8 * 2^8 operand scaling (exact)

    // ---- per-(row, tile) maxes: Hs is dead (post trailing barrier) -> scratch.
    {
        float* red = (float*)Hs;       // [0..255] rowpart [wc][128]; [256..511] colpart [wr][128]
        float rm[4][4];
        #pragma unroll
        for (int i = 0; i < 4; i++) {
            #pragma unroll
            for (int q = 0; q < 4; q++) {
                float m = fmaxf(fmaxf(acc[i][0][q], acc[i][1][q]),
                                fmaxf(acc[i][2][q], acc[i][3][q]));
                #pragma unroll
                for (int off = 1; off <= 8; off <<= 1) { m = fmaxf(m, __shfl_xor(m, off, 64)); }
                rm[i][q] = m;
            }
        }
        if ((lane & 15) == 0) {
            #pragma unroll
            for (int i = 0; i < 4; i++) {
                #pragma unroll
                for (int q = 0; q < 4; q++) {
                    red[wc * 128 + wr * 64 + i * 16 + lk * 4 + q] = rm[i][q];
                }
            }
        }
        float cm[4];
        #pragma unroll
        for (int j = 0; j < 4; j++) {
            float m = acc[0][j][0];
            #pragma unroll
            for (int i = 0; i < 4; i++) {
                #pragma unroll
                for (int q = 0; q < 4; q++) {
                    if (i + q) { m = fmaxf(m, acc[i][j][q]); }
                }
            }
            m = fmaxf(m, __shfl_xor(m, 16, 64));
            m = fmaxf(m, __shfl_xor(m, 32, 64));
            cm[j] = m;
        }
        if (lk == 0) {
            #pragma unroll
            for (int j = 0; j < 4; j++) {
                red[256 + wr * 128 + wc * 64 + j * 16 + lrow] = cm[j];
            }
        }
        __syncthreads();
        if (t < 128) {
            float rmx = fmaxf(red[t], red[128 + t]) * inv;
            int gr = rb + t;
            if (gr < N_NODES) { TM[(size_t)gr * 80 + (cb >> 7)] = fmaxf(rmx, 0.f); }
            float cmx = fmaxf(red[256 + t], red[384 + t]) * inv;
            int gc = cb + t;
            if (gc < N_NODES) { TM[(size_t)gc * 80 + (rb >> 7)] = fmaxf(cmx, 0.f); }
        }
    }

    // epilogue: C/D frag layout col = lane&15, row = (lane>>4)*4 + reg.
    #pragma unroll
    for (int i = 0; i < 4; i++) {
        int rrb = rb + wr * 64 + i * 16 + lk * 4;
        #pragma unroll
        for (int j = 0; j < 4; j++) {
            int cc = cb + wc * 64 + j * 16 + lrow;
            if (cc >= N_NODES) { continue; }
            #pragma unroll
            for (int q = 0; q < 4; q++) {
                int rr = rrb + q;
                if (rr >= N_NODES) { continue; }
                float v = fmaxf(acc[i][j][q] * inv, 0.f);
                S[(size_t)rr * N_NODES + cc] = v;
                S[(size_t)cc * N_NODES + rr] = v;  // mirror (bit-identical dot)
            }
        }
    }
}

// ---------------- generic 128-tile GEMM via fp16-split MFMA ----------------
template<int MODE>
__global__ __launch_bounds__(256) void gemm_mlp(const _Float16* __restrict__ ahi,
                                                const _Float16* __restrict__ alo,
                                                const _Float16* __restrict__ bhi,
                                                const _Float16* __restrict__ blo,
                                                _Float16* __restrict__ chi,
                                                _Float16* __restrict__ clo,
                                                float* __restrict__ cf,
                                                const float* __restrict__ bias,
                                                int on) {
    int rb = blockIdx.y * 128;
    int cb = blockIdx.x * 128;
    __shared__ __align__(16) unsigned short Hs[32768];  // 64 KB
    int t = threadIdx.x;
    int w = t >> 6;
    int lane = t & 63;
    int wr = w >> 1, wc = w & 1;
    int lrow = lane & 15, lk = lane >> 4;
    int lr8 = lane >> 3, ls8 = lane & 7;
    int koffb = ((ls8 ^ lr8) << 4);

    f32x4 acc[4][4];
    #pragma unroll
    for (int i = 0; i < 4; i++) {
        #pragma unroll
        for (int j = 0; j < 4; j++) {
            f32x4 z = {0.f, 0.f, 0.f, 0.f};
            acc[i][j] = z;
        }
    }

    const char* ahp = (const char*)ahi;
    const char* alp = (const char*)alo;
    const char* bhp = (const char*)bhi;
    const char* blp = (const char*)blo;

    #pragma unroll 1
    for (int ks = 0; ks < 4; ks++) {
        int k0b = ks * 128;
        #pragma unroll
        for (int tt = 0; tt < 4; tt++) {
            int c = w * 4 + tt;
            int rowloc = c * 8 + lr8;
            int na = rb + rowloc; if (na > N_NODES - 1) { na = N_NODES - 1; }
            int nb = cb + rowloc;              // Wt rows always valid
            size_t offA = (size_t)na * 512 + k0b + koffb;
            size_t offB = (size_t)nb * 512 + k0b + koffb;
            gload16(ahp + offA, &Hs[0     + c * 512]);
            gload16(alp + offA, &Hs[8192  + c * 512]);
            gload16(bhp + offB, &Hs[16384 + c * 512]);
            gload16(blp + offB, &Hs[24576 + c * 512]);
        }
        __builtin_amdgcn_s_waitcnt(0);
        __syncthreads();
        #pragma unroll 1
        for (int kk = 0; kk < 2; kk++) {
            f16x8 ah[4], al[4], bh[4], bl[4];
            #pragma unroll
            for (int i = 0; i < 4; i++) {
                int ar = wr * 64 + i * 16 + lrow;
                int br = wc * 64 + i * 16 + lrow;
                int ps = ((kk * 4 + lk) ^ (lrow & 7)) * 8;
                ah[i] = *(const f16x8*)&Hs[0     + ar * 64 + ps];
                al[i] = *(const f16x8*)&Hs[8192  + ar * 64 + ps];
                bh[i] = *(const f16x8*)&Hs[16384 + br * 64 + ps];
                bl[i] = *(const f16x8*)&Hs[24576 + br * 64 + ps];
            }
            #pragma unroll
            for (int i = 0; i < 4; i++) {
                #pragma unroll
                for (int j = 0; j < 4; j++) {
                    acc[i][j] = __builtin_amdgcn_mfma_f32_16x16x32_f16(ah[i], bh[j], acc[i][j], 0, 0, 0);
                    acc[i][j] = __builtin_amdgcn_mfma_f32_16x16x32_f16(ah[i], bl[j], acc[i][j], 0, 0, 0);
                    acc[i][j] = __builtin_amdgcn_mfma_f32_16x16x32_f16(al[i], bh[j], acc[i][j], 0, 0, 0);
                }
            }
        }
        __syncthreads();
    }

    const float inv = 1.0f / 65536.0f;
    #pragma unroll
    for (int i = 0; i < 4; i++) {
        int rrb = rb + wr * 64 + i * 16 + lk * 4;
        #pragma unroll
        for (int j = 0; j < 4; j++) {
            int cc = cb + wc * 64 + j * 16 + lrow;
            if (cc >= on && MODE == 0) { continue; }
            #pragma unroll
            for (int q = 0; q < 4; q++) {
                int rr = rrb + q;
                if (rr >= N_NODES) { continue; }
                if (MODE == 1) {
                    float sv = fmaxf(acc[i][j][q], 0.f) * (1.0f / 256.0f);
                    _Float16 hv = (_Float16)sv;
                    chi[(size_t)rr * 256 + cc] = hv;
                    clo[(size_t)rr * 256 + cc] = (_Float16)(sv - (float)hv);
                } else {
                    float v = acc[i][j][q] * inv;
                    if (bias != nullptr) { v += bias[cc]; }
                    cf[(size_t)rr * on + cc] = v;
                }
            }
        }
    }
}

// ---------------- order-statistic-pruned exact top-30, ties -> HIGHEST index ----------------
// One wave per row. thr = 30th-largest tile-max => {v >= thr} is an exact
// superset of the top-30 (>= 30 tiles each contribute one value >= thr, so the
// 30th row value >= thr; anything < thr can't win even on ties). Parallel
// ballot-free collection (LDS atomic append), then the proven register/LDS
// selection with (value desc, index desc). Fuses row-zero (Adj) + degrees.
// Guard ncand<KTOP covers phantom-inflated boundary tile maxes.
__global__ __launch_bounds__(64) void topk_sel_kernel(float* __restrict__ S,
                                                      const float* __restrict__ TM,
                                                      float* __restrict__ tv,
                                                      int* __restrict__ ti,
                                                      float* __restrict__ deg) {
    __shared__ float cv[CANDCAP];
    __shared__ int ci[CANDCAP];
    __shared__ int cntSh;
    int r = blockIdx.x;
    int lane = threadIdx.x;
    float* row = S + (size_t)r * N_NODES;
    const float* trow = TM + (size_t)r * 80;
    if (lane == 0) { cntSh = 0; }
    __syncthreads();

    float m0 = trow[lane];                                   // tiles 0..63
    float m1 = (lane + 64 < NTILE) ? trow[lane + 64] : -3.f; // tiles 64..78

    // thr = 30th-largest tile max (multiset-exact: invalidate one instance/round)
    float a0 = m0, a1 = m1;
    float thr = -1.f;
    for (int k = 0; k < KTOP; k++) {
        float bm = a0; int bt = lane;
        if (a1 > bm) { bm = a1; bt = lane + 64; }
        #pragma unroll
        for (int off = 32; off > 0; off >>= 1) {
            float ov = __shfl_xor(bm, off, 64);
            int ot = __shfl_xor(bt, off, 64);
            if (ov > bm || (ov == bm && ot > bt)) { bm = ov; bt = ot; }
        }
        thr = bm;
        if (bt == lane) { a0 = -3.f; }
        if (bt == lane + 64) { a1 = -3.f; }
    }

    // collect every value >= thr from qualifying tiles (parallel, no insertion)
    for (int tt = 0; tt < NTILE; tt++) {
        float tm = __shfl((tt < 64) ? m0 : m1, tt & 63, 64);
        if (tm < thr) { continue; }
        int c0 = tt * 128 + lane;
        int c1 = c0 + 64;
        float x0 = (c0 < N_NODES) ? row[c0] : -1.f;
        float x1 = (c1 < N_NODES) ? row[c1] : -1.f;
        if (x0 >= thr) {
            int p = atomicAdd(&cntSh, 1);
            if (p < CANDCAP) { cv[p] = x0; ci[p] = c0; }
        }
        if (x1 >= thr) {
            int p = atomicAdd(&cntSh, 1);
            if (p < CANDCAP) { cv[p] = x1; ci[p] = c1; }
        }
    }
    __syncthreads();
    int ncand = cntSh;
    bool fb = (ncand > CANDCAP) || (ncand < KTOP);

    if (fb) {
        // exact fallback over the intact row (value desc, index desc)
        float rs = 0.f;
        for (int k = 0; k < KTOP; k++) {
            float bv = -1.f; int bi = -1;
            for (int j = lane; j < N_NODES; j += 64) {
                float v = row[j];
                if (v >= bv) { bv = v; bi = j; }
            }
            #pragma unroll
            for (int off = 32; off > 0; off >>= 1) {
                float ov = __shfl_xor(bv, off, 64);
                int oi = __shfl_xor(bi, off, 64);
                if (ov > bv || (ov == bv && oi > bi)) { bv = ov; bi = oi; }
            }
            if (lane == 0) {
                tv[r * KTOP + k] = bv;
                ti[r * KTOP + k] = bi;
                atomicAdd(deg + bi, 0.5f * bv);
                rs += bv;
            }
            if (lane == (bi & 63)) { row[bi] = -1.f; }  // same-lane RAW, ordered
        }
        if (lane == 0) { atomicAdd(deg + r, 0.5f * rs); }
        float4 z = {0.f, 0.f, 0.f, 0.f};
        for (int u = lane; u < NQ4; u += 64) { *(float4*)(row + 4 * u) = z; }
        return;
    }

    // fused Adj-zero: wipe own row (stores drain under selection)
    {
        float4 z = {0.f, 0.f, 0.f, 0.f};
        for (int u = lane; u < NQ4; u += 64) { *(float4*)(row + 4 * u) = z; }
    }

    if (ncand <= 128) {
        // register selection: 2 candidates per lane
        float v0 = -2.f, v1 = -2.f;
        int i0 = -1, i1 = -1;
        if (lane < ncand) { v0 = cv[lane]; i0 = ci[lane]; }
        if (lane + 64 < ncand) { v1 = cv[lane + 64]; i1 = ci[lane + 64]; }
        float rs = 0.f;
        for (int k = 0; k < KTOP; k++) {
            bool sel1 = (v1 > v0) || (v1 == v0 && i1 > i0);
            float bv = sel1 ? v1 : v0;
            int bi = sel1 ? i1 : i0;
            #pragma unroll
            for (int m = 32; m > 0; m >>= 1) {
                float ov = __shfl_xor(bv, m, 64);
                int oi = __shfl_xor(bi, m, 64);
                if (ov > bv || (ov == bv && oi > bi)) { bv = ov; bi = oi; }
            }
            if (lane == 0) {
                tv[r * KTOP + k] = bv;
                ti[r * KTOP + k] = bi;
                atomicAdd(deg + bi, 0.5f * bv);
                rs += bv;
            }
            if (i0 == bi) { v0 = -2.f; }
            if (i1 == bi) { v1 = -2.f; }
        }
        if (lane == 0) { atomicAdd(deg + r, 0.5f * rs); }
        return;
    }

    // 128 < ncand <= CANDCAP: LDS loop (wave-local LDS ops are program-ordered)
    float rs = 0.f;
    for (int k = 0; k < KTOP; k++) {
        float bv = -2.f; int bi = -1; int bq = -1;
        for (int q = lane; q < ncand; q += 64) {
            float v = cv[q]; int idx = ci[q];
            if (v > bv || (v == bv && idx > bi)) { bv = v; bi = idx; bq = q; }
        }
        #pragma unroll
        for (int m = 32; m > 0; m >>= 1) {
            float ov = __shfl_xor(bv, m, 64);
            int oi = __shfl_xor(bi, m, 64);
            int oq = __shfl_xor(bq, m, 64);
            if (ov > bv || (ov == bv && oi > bi)) { bv = ov; bi = oi; bq = oq; }
        }
        if (lane == 0) {
            tv[r * KTOP + k] = bv;
            ti[r * KTOP + k] = bi;
            atomicAdd(deg + bi, 0.5f * bv);
            rs += bv;
            cv[bq] = -2.f;
        }
        __syncthreads();
    }
    if (lane == 0) { atomicAdd(deg + r, 0.5f * rs); }
}

// ---------------- zero fill (fallback path only) ----------------
__global__ __launch_bounds__(256) void zero_fill(float4* __restrict__ p, unsigned int n4) {
    unsigned int i = blockIdx.x * 256u + threadIdx.x;
    unsigned int stride = gridDim.x * 256u;
    float4 z = {0.f, 0.f, 0.f, 0.f};
    for (; i < n4; i += stride) { p[i] = z; }
}

__global__ __launch_bounds__(256) void dis_kernel(const float* __restrict__ deg,
                                                  float* __restrict__ dis) {
    int i = blockIdx.x * 256 + threadIdx.x;
    if (i < N_NODES) {
        float d = deg[i];
        dis[i] = d > 0.f ? 1.f / sqrtf(fmaxf(d, 1e-8f)) : 0.f;
    }
}

// ---------------- CSR build (+ optional fused dense Adj scatter) ----------------
template<int WRITE_ADJ>
__global__ __launch_bounds__(256) void csr_adj(const float* __restrict__ tv,
                                               const int* __restrict__ ti,
                                               const float* __restrict__ dis,
                                               int* __restrict__ cnt,
                                               int* __restrict__ nbr,
                                               float* __restrict__ wgt,
                                               float* __restrict__ Adj) {
    int e = blockIdx.x * 256 + threadIdx.x;
    if (e >= N_NODES * KTOP) { return; }
    int i = e / KTOP;
    int j = ti[e];
    float v = tv[e];
    float vrev = 0.f;
    bool mutual = false;
    const int* tj = ti + (size_t)j * KTOP;
    const float* tvj = tv + (size_t)j * KTOP;
    for (int k = 0; k < KTOP; k++) {
        if (tj[k] == i) { vrev = tvj[k]; mutual = true; }
    }
    float w = 0.5f * (v + vrev) * dis[i] * dis[j];
    int p = atomicAdd(cnt + i, 1);
    if (p < CAP) {
        nbr[(size_t)i * CAP + p] = j;
        wgt[(size_t)i * CAP + p] = w;
    }
    if (!mutual) {
        int p2 = atomicAdd(cnt + j, 1);
        if (p2 < CAP) {
            nbr[(size_t)j * CAP + p2] = i;
            wgt[(size_t)j * CAP + p2] = w;
        }
    }
    if (WRITE_ADJ) {
        Adj[(size_t)i * N_NODES + j] = w;
        Adj[(size_t)j * N_NODES + i] = w;
    }
}

// ---------------- Adj scatter (fallback path only) ----------------
__global__ __launch_bounds__(256) void adj_scatter(const float* __restrict__ tv,
                                                   const int* __restrict__ ti,
                                                   const float* __restrict__ dis,
                                                   float* __restrict__ Adj) {
    int e = blockIdx.x * 256 + threadIdx.x;
    if (e >= N_NODES * KTOP) { return; }
    int i = e / KTOP;
    int j = ti[e];
    float v = tv[e];
    float vrev = 0.f;
    const int* tj = ti + (size_t)j * KTOP;
    const float* tvj = tv + (size_t)j * KTOP;
    for (int k = 0; k < KTOP; k++) {
        if (tj[k] == i) { vrev = tvj[k]; }
    }
    float w = 0.5f * (v + vrev) * dis[i] * dis[j];
    Adj[(size_t)i * N_NODES + j] = w;
    Adj[(size_t)j * N_NODES + i] = w;
}

// ---------------- gather SpMM, 128 channels, relu fused (4x ILP) ----------------
__global__ __launch_bounds__(256) void gather128(const int* __restrict__ cnt,
                                                 const int* __restrict__ nbr,
                                                 const float* __restrict__ wgt,
                                                 const float* __restrict__ T,
                                                 float* __restrict__ Y) {
    int node = blockIdx.x * 2 + (threadIdx.x >> 7);
    int c = threadIdx.x & 127;
    if (node >= N_NODES) { return; }
    int n = cnt[node];
    if (n > CAP) { n = CAP; }
    const int* nb = nbr + (size_t)node * CAP;
    const float* wg = wgt + (size_t)node * CAP;
    float a0 = 0.f, a1 = 0.f, a2 = 0.f, a3 = 0.f;
    int k = 0;
    for (; k + 4 <= n; k += 4) {
        int4 j = *(const int4*)(nb + k);
        float4 w = *(const float4*)(wg + k);
        float t0 = T[(size_t)j.x * 128 + c];
        float t1 = T[(size_t)j.y * 128 + c];
        float t2 = T[(size_t)j.z * 128 + c];
        float t3 = T[(size_t)j.w * 128 + c];
        a0 = fmaf(w.x, t0, a0);
        a1 = fmaf(w.y, t1, a1);
        a2 = fmaf(w.z, t2, a2);
        a3 = fmaf(w.w, t3, a3);
    }
    for (; k < n; k++) { a0 = fmaf(wg[k], T[(size_t)nb[k] * 128 + c], a0); }
    float acc = (a0 + a1) + (a2 + a3);
    Y[(size_t)node * 128 + c] = fmaxf(acc, 0.f);
}

// ---------------- y1[M,128] @ Wg2[128,16] + bg2 -> t2[M,16] ----------------
__global__ __launch_bounds__(256) void gemm16(const float* __restrict__ y1,
                                              const float* __restrict__ Wg2,
                                              const float* __restrict__ bg2,
                                              float* __restrict__ out) {
    __shared__ float Ws[2048];
    __shared__ float Ys[16 * 132];
    int t = threadIdx.x;
    int n0 = blockIdx.x * 16;
    for (int i = t; i < 2048; i += 256) {
        Ws[i] = Wg2[i];
        int rr = i >> 7, cc = i & 127;
        int node = n0 + rr;
        if (node > N_NODES - 1) { node = N_NODES - 1; }
        Ys[rr * 132 + cc] = y1[(size_t)node * 128 + cc];
    }
    __syncthreads();
    int nn = t >> 4;
    int c = t & 15;
    int node = n0 + nn;
    if (node >= N_NODES) { return; }
    const float* yr = Ys + nn * 132;
    float acc = 0.f;
    #pragma unroll 4
    for (int k = 0; k < 128; k++) {
        acc = fmaf(yr[k], Ws[k * 16 + c], acc);
    }
    out[(size_t)node * 16 + c] = acc + bg2[c];
}

// ---------------- gather SpMM, 16 channels (4x ILP) ----------------
__global__ __launch_bounds__(256) void gather16(const int* __restrict__ cnt,
                                                const int* __restrict__ nbr,
                                                const float* __restrict__ wgt,
                                                const float* __restrict__ T,
                                                float* __restrict__ Y) {
    int node = blockIdx.x * 16 + (threadIdx.x >> 4);
    int c = threadIdx.x & 15;
    if (node >= N_NODES) { return; }
    int n = cnt[node];
    if (n > CAP) { n = CAP; }
    const int* nb = nbr + (size_t)node * CAP;
    const float* wg = wgt + (size_t)node * CAP;
    float a0 = 0.f, a1 = 0.f, a2 = 0.f, a3 = 0.f;
    int k = 0;
    for (; k + 4 <= n; k += 4) {
        int4 j = *(const int4*)(nb + k);
        float4 w = *(const float4*)(wg + k);
        float t0 = T[(size_t)j.x * 16 + c];
        float t1 = T[(size_t)j.y * 16 + c];
        float t2 = T[(size_t)j.z * 16 + c];
        float t3 = T[(size_t)j.w * 16 + c];
        a0 = fmaf(w.x, t0, a0);
        a1 = fmaf(w.y, t1, a1);
        a2 = fmaf(w.z, t2, a2);
        a3 = fmaf(w.w, t3, a3);
    }
    for (; k < n; k++) { a0 = fmaf(wg[k], T[(size_t)nb[k] * 16 + c], a0); }
    Y[(size_t)node * 16 + c] = (a0 + a1) + (a2 + a3);
}

extern "C" void kernel_launch(void* const* d_in, const int* in_sizes, int n_in,
                              void* d_out, int out_size, void* d_ws, size_t ws_size,
                              hipStream_t stream) {
    const float* features = (const float*)d_in[0];
    const float* x   = (const float*)d_in[1];
    const float* W1  = (const float*)d_in[2];
    const float* W2  = (const float*)d_in[3];
    const float* Wg1 = (const float*)d_in[4];
    const float* bg1 = (const float*)d_in[5];
    const float* Wg2 = (const float*)d_in[6];
    const float* bg2 = (const float*)d_in[7];

    float* ws = (float*)d_ws;
    // region A [0, 2.56M) floats: fsp -> hbuf -> tmax -> xsp
    // region B [2.56M, 5.12M) floats: h1sp -> Hhi/Hlo -> t1 | y1
    float* hbuf = ws;
    float* tmax = ws;                          // 800,000 f (10000 x 80), over dead hbuf
    float* tv   = ws + 5120000;               // 300,000 f
    int*   ti   = (int*)(ws + 5420000);       // 300,000 i
    float* deg  = ws + 5720000;               // 10,000 f
    float* dis  = ws + 5730000;               // 10,000 f
    float* t2   = ws + 5740000;               // 160,000 f (W-splits live here early)
    int*   cnt  = (int*)(ws + 5900000);       // 10,000 i
    float* t1   = ws + 2560000;               // Hhi region, after gemm_s dead
    float* y1   = ws + 3840000;               // Hlo region, after gemm_s dead

    _Float16* fsphi = (_Float16*)ws;
    _Float16* fsplo = fsphi + 2560000;
    _Float16* xsphi = (_Float16*)ws;                    // after tmax dead (post topk)
    _Float16* xsplo = xsphi + 2560000;
    _Float16* h1hi = (_Float16*)(ws + 2560000);
    _Float16* h1lo = h1hi + 2560000;
    _Float16* Hhi  = (_Float16*)(ws + 2560000);
    _Float16* Hlo  = Hhi + 2560000;
    _Float16* W1thi = (_Float16*)(ws + 5740000);        // 65,536 halves each
    _Float16* W1tlo = W1thi + 65536;
    _Float16* W2thi = W1thi + 131072;
    _Float16* W2tlo = W1thi + 196608;
    _Float16* Wg1thi = (_Float16*)(ws + 5740000);       // reuse after MLP chain (128x256)
    _Float16* Wg1tlo = Wg1thi + 32768;

    float* out_f = (float*)d_out;             // 160,000 f32
    float* Adj   = out_f + 160000;            // 1e8 f32 = 400 MB
    float* Sbuf  = Adj;                       // S until topk (topk zeroes it)

    // CSR placement: workspace if it fits, else alias Adj (zero+scatter at end)
    size_t csr_off = 5910000;                                  // floats
    size_t csr_need = (csr_off + (size_t)N_NODES * CAP * 2) * sizeof(float);
    bool csr_in_ws = ws_size >= csr_need;
    int*   nbr = csr_in_ws ? (int*)(ws + csr_off) : (int*)Adj;
    float* wgt = csr_in_ws ? (float*)(ws + csr_off + (size_t)N_NODES * CAP)
                           : (float*)(Adj + (size_t)N_NODES * CAP);

    // ---- MLP chain via fp16-split MFMA ----
    split_rows<<<dim3(10000), dim3(256), 0, stream>>>(features, fsphi, fsplo, 2560000);
    splitWT<<<dim3(256), dim3(256), 0, stream>>>(W1, W1thi, W1tlo, 256);
    splitWT<<<dim3(256), dim3(256), 0, stream>>>(W2, W2thi, W2tlo, 256);
    gemm_mlp<1><<<dim3(2, 79), dim3(256), 0, stream>>>(
        fsphi, fsplo, W1thi, W1tlo, h1hi, h1lo, (float*)nullptr, (const float*)nullptr, 256);
    gemm_mlp<0><<<dim3(2, 79), dim3(256), 0, stream>>>(
        h1hi, h1lo, W2thi, W2tlo, (_Float16*)nullptr, (_Float16*)nullptr, hbuf,
        (const float*)nullptr, 256);
    rownorm_np_kernel<<<dim3(N_NODES), dim3(256), 0, stream>>>(hbuf, Hhi, Hlo);

    // ---- Wg1 split (W1t/W2t dead) ----
    splitWT<<<dim3(128), dim3(256), 0, stream>>>(Wg1, Wg1thi, Wg1tlo, 128);

    // ---- S (triangle + mirror) + tile maxes; pruned exact top-30 + zero + degrees ----
    gemm_s_f16<<<dim3(79, 79), dim3(256), 0, stream>>>(Hhi, Hlo, Sbuf, tmax);
    hipMemsetAsync(deg, 0, N_NODES * sizeof(float), stream);
    topk_sel_kernel<<<dim3(N_NODES), dim3(64), 0, stream>>>(Sbuf, tmax, tv, ti, deg);

    // ---- x split (tmax dead) + GCN layer-1 GEMM ----
    split_rows<<<dim3(10000), dim3(256), 0, stream>>>(x, xsphi, xsplo, 2560000);
    gemm_mlp<0><<<dim3(1, 79), dim3(256), 0, stream>>>(
        xsphi, xsplo, Wg1thi, Wg1tlo, (_Float16*)nullptr, (_Float16*)nullptr, t1, bg1, 128);

    dis_kernel<<<dim3((N_NODES + 255) / 256), dim3(256), 0, stream>>>(deg, dis);

    // ---- CSR build (+ fused Adj scatter when CSR lives in ws; S already zeroed) ----
    hipMemsetAsync(cnt, 0, N_NODES * sizeof(int), stream);
    int eblocks = (N_NODES * KTOP + 255) / 256;
    if (csr_in_ws) {
        csr_adj<1><<<dim3(eblocks), dim3(256), 0, stream>>>(tv, ti, dis, cnt, nbr, wgt, Adj);
    } else {
        csr_adj<0><<<dim3(eblocks), dim3(256), 0, stream>>>(tv, ti, dis, cnt, nbr, wgt, Adj);
    }

    // ---- GCN layers via gather SpMM ----
    gather128<<<dim3(N_NODES / 2), dim3(256), 0, stream>>>(cnt, nbr, wgt, t1, y1);
    gemm16<<<dim3(625), dim3(256), 0, stream>>>(y1, Wg2, bg2, t2);
    gather16<<<dim3((N_NODES + 15) / 16), dim3(256), 0, stream>>>(cnt, nbr, wgt, t2, out_f);

    // ---- fallback: CSR aliased Adj -> zero full Adj and scatter dense ----
    if (!csr_in_ws) {
        zero_fill<<<dim3(2048), dim3(256), 0, stream>>>(
            (float4*)Adj, (unsigned int)((size_t)N_NODES * N_NODES / 4));
        adj_scatter<<<dim3(eblocks), dim3(256), 0, stream>>>(tv, ti, dis, Adj);
    }
}

// Round 7
// 1032.859 us; speedup vs baseline: 1.2700x; 1.0789x over previous
//
#include <hip/hip_runtime.h>
#include <hip/hip_bf16.h>
#include <cstddef>

#define N_NODES 10000
#define KTOP 30
#define CAP 2048     // max CSR row length
#define CANDCAP 512
#define NQ4 (N_NODES / 4)   // 2500 float4 per row
#define NTILE 79     // ceil(10000/128)

typedef _Float16 f16x8 __attribute__((ext_vector_type(8)));
typedef float f32x4 __attribute__((ext_vector_type(4)));

// ---------------- fp16 2-way split helpers ----------------
// split(v): hi = f16(v*256), lo = f16(v*256 - hi). Scale 2^8 keeps values in
// the fp16 normal range; undone by 2^-16 after the hi/lo product GEMM.
__global__ __launch_bounds__(256) void split_rows(const float* __restrict__ src,
                                                  _Float16* __restrict__ hi,
                                                  _Float16* __restrict__ lo,
                                                  int n) {
    int i = blockIdx.x * 256 + threadIdx.x;
    if (i >= n) { return; }
    float v = src[i] * 256.0f;
    _Float16 h = (_Float16)v;
    hi[i] = h;
    lo[i] = (_Float16)(v - (float)h);
}

// W[k][n] (256 x N) -> Wt[n][k] split (so GEMM B-addressing == A-addressing)
__global__ __launch_bounds__(256) void splitWT(const float* __restrict__ W,
                                               _Float16* __restrict__ hi,
                                               _Float16* __restrict__ lo,
                                               int N) {
    int n = blockIdx.x;
    int k = threadIdx.x;
    float v = W[k * N + n] * 256.0f;
    _Float16 h = (_Float16)v;
    hi[n * 256 + k] = h;
    lo[n * 256 + k] = (_Float16)(v - (float)h);
}

// ---------------- row normalize, numpy-pairwise-exact semantics ----------------
__global__ __launch_bounds__(256) void rownorm_np_kernel(const float* __restrict__ h,
                                                         _Float16* __restrict__ hhi,
                                                         _Float16* __restrict__ hlo) {
    __shared__ float row[256];
    __shared__ float denom_sh;
    int r = blockIdx.x;
    int t = threadIdx.x;
    const float* p = h + (size_t)r * 256;
    row[t] = p[t];
    __syncthreads();
    if (t < 16) {
        int half = t >> 3;
        int j = t & 7;
        const float* a = row + half * 128 + j;
        float rr = __fmul_rn(a[0], a[0]);
        #pragma unroll
        for (int i = 1; i < 16; i++) {
            rr = __fadd_rn(rr, __fmul_rn(a[i * 8], a[i * 8]));
        }
        #pragma unroll
        for (int off = 1; off <= 8; off <<= 1) {
            rr = __fadd_rn(rr, __shfl_xor(rr, off, 64));
        }
        if (t == 0) { denom_sh = __fadd_rn(__fsqrt_rn(rr), 1e-8f); }
    }
    __syncthreads();
    float v = __fdiv_rn(row[t], denom_sh);
    float sc = v * 256.0f;                 // exact (power-of-2 scale)
    _Float16 hv = (_Float16)sc;            // RNE to fp16
    float rem = sc - (float)hv;            // exact (Sterbenz-range)
    hhi[(size_t)r * 256 + t] = hv;
    hlo[(size_t)r * 256 + t] = (_Float16)rem;
}

// ---------------- global_load_lds helper ----------------
__device__ __forceinline__ void gload16(const void* g, void* l) {
    __builtin_amdgcn_global_load_lds(
        (const __attribute__((address_space(1))) unsigned int*)g,
        (__attribute__((address_space(3))) unsigned int*)l, 16, 0, 0);
}

// ---------------- S tile GEMM via fp16-split MFMA, double-buffered pipeline ----------------
// Emits per-(row, col-tile) maxes of relu(S) into TM[10000][80]. Mirror writes
// use float4 (4 consecutive rr per (i,j)) to avoid 4B-scattered stores.
__global__ __launch_bounds__(256) void gemm_s_f16(const _Float16* __restrict__ hi,
                                                  const _Float16* __restrict__ lo,
                                                  float* __restrict__ S,
                                                  float* __restrict__ TM) {
    int rb = blockIdx.y * 128;
    int cb = blockIdx.x * 128;
    if (cb < rb) { return; }
    __shared__ __align__(16) unsigned short Hs[2][16384];  // 2 x 32 KB (A at 0, B at 8192)
    int t = threadIdx.x;
    int w = t >> 6;
    int lane = t & 63;
    int wr = w >> 1, wc = w & 1;          // wave -> 64x64 quadrant
    int lrow = lane & 15, lk = lane >> 4; // mfma A/B fragment mapping
    int lr8 = lane >> 3, ls8 = lane & 7;  // staging: 8 rows x 8 phys slots per 1KB chunk

    int slog = ls8 ^ lr8;                  // logical slot this lane sources
    const char* srcp = (slog < 4) ? (const char*)hi : (const char*)lo;
    int koff = (slog & 3) * 16;            // 16B k-slot within the stage's 64B range
    int cbase = w * 8;

    f32x4 acc[4][4];
    #pragma unroll
    for (int i = 0; i < 4; i++) {
        #pragma unroll
        for (int j = 0; j < 4; j++) {
            f32x4 z = {0.f, 0.f, 0.f, 0.f};
            acc[i][j] = z;
        }
    }

    auto STAGE = [&](int sidx, int b) {
        int kb = sidx * 64;                // byte offset of stage's k-range (32 halves)
        #pragma unroll
        for (int tt = 0; tt < 8; tt++) {
            int c = cbase + tt;            // chunk 0..31
            int rl = ((c & 15) << 3) + lr8;
            int node = ((c >> 4) ? cb : rb) + rl;
            if (node > N_NODES - 1) { node = N_NODES - 1; }
            gload16(srcp + (size_t)node * 512 + kb + koff, &Hs[b][c << 9]);
        }
    };

    STAGE(0, 0);
    #pragma unroll 1
    for (int s = 0; s < 8; s++) {
        int b = s & 1;
        if (s < 7) { STAGE(s + 1, b ^ 1); }
        __builtin_amdgcn_sched_barrier(0);
        if (s < 7) { asm volatile("s_waitcnt vmcnt(8)" ::: "memory"); }
        else       { asm volatile("s_waitcnt vmcnt(0)" ::: "memory"); }
        __builtin_amdgcn_s_barrier();
        __builtin_amdgcn_sched_barrier(0);
        f16x8 ah[4], al[4], bh[4], bl[4];
        #pragma unroll
        for (int i = 0; i < 4; i++) {
            int ar = wr * 64 + i * 16 + lrow;
            int br = wc * 64 + i * 16 + lrow;
            int ra7 = ar & 7, rb7 = br & 7;
            ah[i] = *(const f16x8*)&Hs[b][ar * 64 + ((lk ^ ra7) << 3)];
            al[i] = *(const f16x8*)&Hs[b][ar * 64 + (((lk + 4) ^ ra7) << 3)];
            bh[i] = *(const f16x8*)&Hs[b][8192 + br * 64 + ((lk ^ rb7) << 3)];
            bl[i] = *(const f16x8*)&Hs[b][8192 + br * 64 + (((lk + 4) ^ rb7) << 3)];
        }
        #pragma unroll
        for (int i = 0; i < 4; i++) {
            #pragma unroll
            for (int j = 0; j < 4; j++) {
                acc[i][j] = __builtin_amdgcn_mfma_f32_16x16x32_f16(ah[i], bh[j], acc[i][j], 0, 0, 0);
                acc[i][j] = __builtin_amdgcn_mfma_f32_16x16x32_f16(ah[i], bl[j], acc[i][j], 0, 0, 0);
                acc[i][j] = __builtin_amdgcn_mfma_f32_16x16x32_f16(al[i], bh[j], acc[i][j], 0, 0, 0);
            }
        }
        __builtin_amdgcn_sched_barrier(0);
        __builtin_amdgcn_s_barrier();
    }

    const float inv = 1.0f / 65536.0f;  // undo 2^8 * 2^8 operand scaling (exact)

    // ---- per-(row, tile) maxes: Hs is dead (post trailing barrier) -> scratch.
    {
        float* red = (float*)Hs;       // [0..255] rowpart [wc][128]; [256..511] colpart [wr][128]
        float rm[4][4];
        #pragma unroll
        for (int i = 0; i < 4; i++) {
            #pragma unroll
            for (int q = 0; q < 4; q++) {
                float m = fmaxf(fmaxf(acc[i][0][q], acc[i][1][q]),
                                fmaxf(acc[i][2][q], acc[i][3][q]));
                #pragma unroll
                for (int off = 1; off <= 8; off <<= 1) { m = fmaxf(m, __shfl_xor(m, off, 64)); }
                rm[i][q] = m;
            }
        }
        if ((lane & 15) == 0) {
            #pragma unroll
            for (int i = 0; i < 4; i++) {
                #pragma unroll
                for (int q = 0; q < 4; q++) {
                    red[wc * 128 + wr * 64 + i * 16 + lk * 4 + q] = rm[i][q];
                }
            }
        }
        float cm[4];
        #pragma unroll
        for (int j = 0; j < 4; j++) {
            float m = acc[0][j][0];
            #pragma unroll
            for (int i = 0; i < 4; i++) {
                #pragma unroll
                for (int q = 0; q < 4; q++) {
                    if (i + q) { m = fmaxf(m, acc[i][j][q]); }
                }
            }
            m = fmaxf(m, __shfl_xor(m, 16, 64));
            m = fmaxf(m, __shfl_xor(m, 32, 64));
            cm[j] = m;
        }
        if (lk == 0) {
            #pragma unroll
            for (int j = 0; j < 4; j++) {
                red[256 + wr * 128 + wc * 64 + j * 16 + lrow] = cm[j];
            }
        }
        __syncthreads();
        if (t < 128) {
            float rmx = fmaxf(red[t], red[128 + t]) * inv;
            int gr = rb + t;
            if (gr < N_NODES) { TM[(size_t)gr * 80 + (cb >> 7)] = fmaxf(rmx, 0.f); }
            float cmx = fmaxf(red[256 + t], red[384 + t]) * inv;
            int gc = cb + t;
            if (gc < N_NODES) { TM[(size_t)gc * 80 + (rb >> 7)] = fmaxf(cmx, 0.f); }
        }
    }

    // epilogue: C/D frag layout col = lane&15, row = (lane>>4)*4 + reg.
    // normal: lane-coalesced 4B stores; mirror: float4 over the 4 consecutive rr.
    #pragma unroll
    for (int i = 0; i < 4; i++) {
        int rrb = rb + wr * 64 + i * 16 + lk * 4;
        #pragma unroll
        for (int j = 0; j < 4; j++) {
            int cc = cb + wc * 64 + j * 16 + lrow;
            if (cc >= N_NODES) { continue; }
            float4 mv;
            float* mp = &mv.x;
            #pragma unroll
            for (int q = 0; q < 4; q++) {
                float v = fmaxf(acc[i][j][q] * inv, 0.f);
                mp[q] = v;
                int rr = rrb + q;
                if (rr < N_NODES) { S[(size_t)rr * N_NODES + cc] = v; }
            }
            if (rrb + 3 < N_NODES) {
                *(float4*)(S + (size_t)cc * N_NODES + rrb) = mv;  // 16B aligned: N*4%16==0, rrb%4==0
            } else {
                #pragma unroll
                for (int q = 0; q < 4; q++) {
                    int rr = rrb + q;
                    if (rr < N_NODES) { S[(size_t)cc * N_NODES + rr] = mp[q]; }
                }
            }
        }
    }
}

// ---------------- generic 128-tile GEMM via fp16-split MFMA ----------------
template<int MODE>
__global__ __launch_bounds__(256) void gemm_mlp(const _Float16* __restrict__ ahi,
                                                const _Float16* __restrict__ alo,
                                                const _Float16* __restrict__ bhi,
                                                const _Float16* __restrict__ blo,
                                                _Float16* __restrict__ chi,
                                                _Float16* __restrict__ clo,
                                                float* __restrict__ cf,
                                                const float* __restrict__ bias,
                                                int on) {
    int rb = blockIdx.y * 128;
    int cb = blockIdx.x * 128;
    __shared__ __align__(16) unsigned short Hs[32768];  // 64 KB
    int t = threadIdx.x;
    int w = t >> 6;
    int lane = t & 63;
    int wr = w >> 1, wc = w & 1;
    int lrow = lane & 15, lk = lane >> 4;
    int lr8 = lane >> 3, ls8 = lane & 7;
    int koffb = ((ls8 ^ lr8) << 4);

    f32x4 acc[4][4];
    #pragma unroll
    for (int i = 0; i < 4; i++) {
        #pragma unroll
        for (int j = 0; j < 4; j++) {
            f32x4 z = {0.f, 0.f, 0.f, 0.f};
            acc[i][j] = z;
        }
    }

    const char* ahp = (const char*)ahi;
    const char* alp = (const char*)alo;
    const char* bhp = (const char*)bhi;
    const char* blp = (const char*)blo;

    #pragma unroll 1
    for (int ks = 0; ks < 4; ks++) {
        int k0b = ks * 128;
        #pragma unroll
        for (int tt = 0; tt < 4; tt++) {
            int c = w * 4 + tt;
            int rowloc = c * 8 + lr8;
            int na = rb + rowloc; if (na > N_NODES - 1) { na = N_NODES - 1; }
            int nb = cb + rowloc;              // Wt rows always valid
            size_t offA = (size_t)na * 512 + k0b + koffb;
            size_t offB = (size_t)nb * 512 + k0b + koffb;
            gload16(ahp + offA, &Hs[0     + c * 512]);
            gload16(alp + offA, &Hs[8192  + c * 512]);
            gload16(bhp + offB, &Hs[16384 + c * 512]);
            gload16(blp + offB, &Hs[24576 + c * 512]);
        }
        __builtin_amdgcn_s_waitcnt(0);
        __syncthreads();
        #pragma unroll 1
        for (int kk = 0; kk < 2; kk++) {
            f16x8 ah[4], al[4], bh[4], bl[4];
            #pragma unroll
            for (int i = 0; i < 4; i++) {
                int ar = wr * 64 + i * 16 + lrow;
                int br = wc * 64 + i * 16 + lrow;
                int ps = ((kk * 4 + lk) ^ (lrow & 7)) * 8;
                ah[i] = *(const f16x8*)&Hs[0     + ar * 64 + ps];
                al[i] = *(const f16x8*)&Hs[8192  + ar * 64 + ps];
                bh[i] = *(const f16x8*)&Hs[16384 + br * 64 + ps];
                bl[i] = *(const f16x8*)&Hs[24576 + br * 64 + ps];
            }
            #pragma unroll
            for (int i = 0; i < 4; i++) {
                #pragma unroll
                for (int j = 0; j < 4; j++) {
                    acc[i][j] = __builtin_amdgcn_mfma_f32_16x16x32_f16(ah[i], bh[j], acc[i][j], 0, 0, 0);
                    acc[i][j] = __builtin_amdgcn_mfma_f32_16x16x32_f16(ah[i], bl[j], acc[i][j], 0, 0, 0);
                    acc[i][j] = __builtin_amdgcn_mfma_f32_16x16x32_f16(al[i], bh[j], acc[i][j], 0, 0, 0);
                }
            }
        }
        __syncthreads();
    }

    const float inv = 1.0f / 65536.0f;
    #pragma unroll
    for (int i = 0; i < 4; i++) {
        int rrb = rb + wr * 64 + i * 16 + lk * 4;
        #pragma unroll
        for (int j = 0; j < 4; j++) {
            int cc = cb + wc * 64 + j * 16 + lrow;
            if (cc >= on && MODE == 0) { continue; }
            #pragma unroll
            for (int q = 0; q < 4; q++) {
                int rr = rrb + q;
                if (rr >= N_NODES) { continue; }
                if (MODE == 1) {
                    float sv = fmaxf(acc[i][j][q], 0.f) * (1.0f / 256.0f);
                    _Float16 hv = (_Float16)sv;
                    chi[(size_t)rr * 256 + cc] = hv;
                    clo[(size_t)rr * 256 + cc] = (_Float16)(sv - (float)hv);
                } else {
                    float v = acc[i][j][q] * inv;
                    if (bias != nullptr) { v += bias[cc]; }
                    cf[(size_t)rr * on + cc] = v;
                }
            }
        }
    }
}

// ---------------- order-statistic-pruned exact top-30, ties -> HIGHEST index ----------------
// 256 threads/row. thr = 30th-largest tile-max (exact superset bound), found by
// RANK (parallel 79-scan, no serial argmax chain). Collection distributed over
// 4 waves; row-zero by all 256 threads; selection on wave 0 (register path
// <=128 cands, barrier-free LDS path otherwise). Fuses degrees (deg pre-zeroed).
__global__ __launch_bounds__(256) void topk_sel_kernel(float* __restrict__ S,
                                                       const float* __restrict__ TM,
                                                       float* __restrict__ tv,
                                                       int* __restrict__ ti,
                                                       float* __restrict__ deg) {
    __shared__ float cv[CANDCAP];
    __shared__ int ci[CANDCAP];
    __shared__ float tmv[NTILE];
    __shared__ int cntSh;
    __shared__ float thrSh;
    __shared__ float wv[4];
    __shared__ int wi[4];
    int t = threadIdx.x;
    int w = t >> 6;
    int lane = t & 63;
    int r = blockIdx.x;
    float* row = S + (size_t)r * N_NODES;
    const float* trow = TM + (size_t)r * 80;
    if (t == 0) { cntSh = 0; }
    if (t < NTILE) { tmv[t] = trow[t]; }
    __syncthreads();

    // thr by rank: lane ranks its <=2 tile-max values against all 79
    if (t < 64) {
        float v0 = tmv[lane];
        float v1 = (lane + 64 < NTILE) ? tmv[lane + 64] : -3.f;
        int rk0 = 0, rk1 = 0;
        for (int j = 0; j < NTILE; j++) {
            float vj = tmv[j];
            if (vj > v0 || (vj == v0 && j > lane)) { rk0++; }
            if (vj > v1 || (vj == v1 && j > lane + 64)) { rk1++; }
        }
        if (rk0 == KTOP - 1) { thrSh = v0; }
        if (lane + 64 < NTILE && rk1 == KTOP - 1) { thrSh = v1; }
    }
    __syncthreads();
    float thr = thrSh;

    // collection: wave w handles tiles w, w+4, ... (parallel, no insertion)
    for (int tt = w; tt < NTILE; tt += 4) {
        if (tmv[tt] < thr) { continue; }
        int c0 = tt * 128 + lane;
        int c1 = c0 + 64;
        float x0 = (c0 < N_NODES) ? row[c0] : -1.f;
        float x1 = (c1 < N_NODES) ? row[c1] : -1.f;
        if (x0 >= thr) {
            int p = atomicAdd(&cntSh, 1);
            if (p < CANDCAP) { cv[p] = x0; ci[p] = c0; }
        }
        if (x1 >= thr) {
            int p = atomicAdd(&cntSh, 1);
            if (p < CANDCAP) { cv[p] = x1; ci[p] = c1; }
        }
    }
    __syncthreads();
    int ncand = cntSh;
    bool fb = (ncand > CANDCAP) || (ncand < KTOP);

    if (fb) {
        // exact fallback over the intact row (value desc, index desc), 256t
        float rs = 0.f;
        for (int k = 0; k < KTOP; k++) {
            float bv = -1.f;
            int bi = -1;
            for (int j = t; j < N_NODES; j += 256) {
                float v = row[j];
                if (v >= bv) { bv = v; bi = j; }
            }
            #pragma unroll
            for (int off = 32; off > 0; off >>= 1) {
                float ov = __shfl_down(bv, off, 64);
                int oi = __shfl_down(bi, off, 64);
                if (ov > bv || (ov == bv && oi > bi)) { bv = ov; bi = oi; }
            }
            if (lane == 0) { wv[w] = bv; wi[w] = bi; }
            __syncthreads();
            if (t == 0) {
                float fv = wv[0];
                int fi = wi[0];
                for (int q = 1; q < 4; q++) {
                    if (wv[q] > fv || (wv[q] == fv && wi[q] > fi)) { fv = wv[q]; fi = wi[q]; }
                }
                tv[r * KTOP + k] = fv;
                ti[r * KTOP + k] = fi;
                atomicAdd(deg + fi, 0.5f * fv);
                rs += fv;
                row[fi] = -1.f;
            }
            __syncthreads();
        }
        if (t == 0) { atomicAdd(deg + r, 0.5f * rs); }
        float4 z = {0.f, 0.f, 0.f, 0.f};
        for (int u = t; u < NQ4; u += 256) { *(float4*)(row + 4 * u) = z; }
        return;
    }

    // fused Adj-zero: wipe own row with all 256 threads
    {
        float4 z = {0.f, 0.f, 0.f, 0.f};
        for (int u = t; u < NQ4; u += 256) { *(float4*)(row + 4 * u) = z; }
    }

    // selection: wave 0 only, barrier-free (intra-wave LDS is program-ordered)
    if (t < 64) {
        float rs = 0.f;
        if (ncand <= 128) {
            float v0 = -2.f, v1 = -2.f;
            int i0 = -1, i1 = -1;
            if (lane < ncand) { v0 = cv[lane]; i0 = ci[lane]; }
            if (lane + 64 < ncand) { v1 = cv[lane + 64]; i1 = ci[lane + 64]; }
            for (int k = 0; k < KTOP; k++) {
                bool sel1 = (v1 > v0) || (v1 == v0 && i1 > i0);
                float bv = sel1 ? v1 : v0;
                int bi = sel1 ? i1 : i0;
                #pragma unroll
                for (int m = 32; m > 0; m >>= 1) {
                    float ov = __shfl_xor(bv, m, 64);
                    int oi = __shfl_xor(bi, m, 64);
                    if (ov > bv || (ov == bv && oi > bi)) { bv = ov; bi = oi; }
                }
                if (lane == 0) {
                    tv[r * KTOP + k] = bv;
                    ti[r * KTOP + k] = bi;
                    atomicAdd(deg + bi, 0.5f * bv);
                    rs += bv;
                }
                if (i0 == bi) { v0 = -2.f; }
                if (i1 == bi) { v1 = -2.f; }
            }
        } else {
            for (int k = 0; k < KTOP; k++) {
                float bv = -2.f;
                int bi = -1;
                int bq = -1;
                for (int q = lane; q < ncand; q += 64) {
                    float v = cv[q];
                    int idx = ci[q];
                    if (v > bv || (v == bv && idx > bi)) { bv = v; bi = idx; bq = q; }
                }
                #pragma unroll
                for (int m = 32; m > 0; m >>= 1) {
                    float ov = __shfl_xor(bv, m, 64);
                    int oi = __shfl_xor(bi, m, 64);
                    int oq = __shfl_xor(bq, m, 64);
                    if (ov > bv || (ov == bv && oi > bi)) { bv = ov; bi = oi; bq = oq; }
                }
                if (lane == 0) {
                    tv[r * KTOP + k] = bv;
                    ti[r * KTOP + k] = bi;
                    atomicAdd(deg + bi, 0.5f * bv);
                    rs += bv;
                    cv[bq] = -2.f;
                }
            }
        }
        if (lane == 0) { atomicAdd(deg + r, 0.5f * rs); }
    }
}

// ---------------- zero fill (fallback path only) ----------------
__global__ __launch_bounds__(256) void zero_fill(float4* __restrict__ p, unsigned int n4) {
    unsigned int i = blockIdx.x * 256u + threadIdx.x;
    unsigned int stride = gridDim.x * 256u;
    float4 z = {0.f, 0.f, 0.f, 0.f};
    for (; i < n4; i += stride) { p[i] = z; }
}

__global__ __launch_bounds__(256) void dis_kernel(const float* __restrict__ deg,
                                                  float* __restrict__ dis) {
    int i = blockIdx.x * 256 + threadIdx.x;
    if (i < N_NODES) {
        float d = deg[i];
        dis[i] = d > 0.f ? 1.f / sqrtf(fmaxf(d, 1e-8f)) : 0.f;
    }
}

// ---------------- CSR build (+ optional fused dense Adj scatter) ----------------
template<int WRITE_ADJ>
__global__ __launch_bounds__(256) void csr_adj(const float* __restrict__ tv,
                                               const int* __restrict__ ti,
                                               const float* __restrict__ dis,
                                               int* __restrict__ cnt,
                                               int* __restrict__ nbr,
                                               float* __restrict__ wgt,
                                               float* __restrict__ Adj) {
    int e = blockIdx.x * 256 + threadIdx.x;
    if (e >= N_NODES * KTOP) { return; }
    int i = e / KTOP;
    int j = ti[e];
    float v = tv[e];
    float vrev = 0.f;
    bool mutual = false;
    const int* tj = ti + (size_t)j * KTOP;
    const float* tvj = tv + (size_t)j * KTOP;
    for (int k = 0; k < KTOP; k++) {
        if (tj[k] == i) { vrev = tvj[k]; mutual = true; }
    }
    float w = 0.5f * (v + vrev) * dis[i] * dis[j];
    int p = atomicAdd(cnt + i, 1);
    if (p < CAP) {
        nbr[(size_t)i * CAP + p] = j;
        wgt[(size_t)i * CAP + p] = w;
    }
    if (!mutual) {
        int p2 = atomicAdd(cnt + j, 1);
        if (p2 < CAP) {
            nbr[(size_t)j * CAP + p2] = i;
            wgt[(size_t)j * CAP + p2] = w;
        }
    }
    if (WRITE_ADJ) {
        Adj[(size_t)i * N_NODES + j] = w;
        Adj[(size_t)j * N_NODES + i] = w;
    }
}

// ---------------- Adj scatter (fallback path only) ----------------
__global__ __launch_bounds__(256) void adj_scatter(const float* __restrict__ tv,
                                                   const int* __restrict__ ti,
                                                   const float* __restrict__ dis,
                                                   float* __restrict__ Adj) {
    int e = blockIdx.x * 256 + threadIdx.x;
    if (e >= N_NODES * KTOP) { return; }
    int i = e / KTOP;
    int j = ti[e];
    float v = tv[e];
    float vrev = 0.f;
    const int* tj = ti + (size_t)j * KTOP;
    const float* tvj = tv + (size_t)j * KTOP;
    for (int k = 0; k < KTOP; k++) {
        if (tj[k] == i) { vrev = tvj[k]; }
    }
    float w = 0.5f * (v + vrev) * dis[i] * dis[j];
    Adj[(size_t)i * N_NODES + j] = w;
    Adj[(size_t)j * N_NODES + i] = w;
}

// ---------------- gather SpMM, 128 channels, relu fused (4x ILP) ----------------
__global__ __launch_bounds__(256) void gather128(const int* __restrict__ cnt,
                                                 const int* __restrict__ nbr,
                                                 const float* __restrict__ wgt,
                                                 const float* __restrict__ T,
                                                 float* __restrict__ Y) {
    int node = blockIdx.x * 2 + (threadIdx.x >> 7);
    int c = threadIdx.x & 127;
    if (node >= N_NODES) { return; }
    int n = cnt[node];
    if (n > CAP) { n = CAP; }
    const int* nb = nbr + (size_t)node * CAP;
    const float* wg = wgt + (size_t)node * CAP;
    float a0 = 0.f, a1 = 0.f, a2 = 0.f, a3 = 0.f;
    int k = 0;
    for (; k + 4 <= n; k += 4) {
        int4 j = *(const int4*)(nb + k);
        float4 w = *(const float4*)(wg + k);
        float t0 = T[(size_t)j.x * 128 + c];
        float t1 = T[(size_t)j.y * 128 + c];
        float t2 = T[(size_t)j.z * 128 + c];
        float t3 = T[(size_t)j.w * 128 + c];
        a0 = fmaf(w.x, t0, a0);
        a1 = fmaf(w.y, t1, a1);
        a2 = fmaf(w.z, t2, a2);
        a3 = fmaf(w.w, t3, a3);
    }
    for (; k < n; k++) { a0 = fmaf(wg[k], T[(size_t)nb[k] * 128 + c], a0); }
    float acc = (a0 + a1) + (a2 + a3);
    Y[(size_t)node * 128 + c] = fmaxf(acc, 0.f);
}

// ---------------- y1[M,128] @ Wg2[128,16] + bg2 -> t2[M,16] ----------------
__global__ __launch_bounds__(256) void gemm16(const float* __restrict__ y1,
                                              const float* __restrict__ Wg2,
                                              const float* __restrict__ bg2,
                                              float* __restrict__ out) {
    __shared__ float Ws[2048];
    __shared__ float Ys[16 * 132];
    int t = threadIdx.x;
    int n0 = blockIdx.x * 16;
    for (int i = t; i < 2048; i += 256) {
        Ws[i] = Wg2[i];
        int rr = i >> 7, cc = i & 127;
        int node = n0 + rr;
        if (node > N_NODES - 1) { node = N_NODES - 1; }
        Ys[rr * 132 + cc] = y1[(size_t)node * 128 + cc];
    }
    __syncthreads();
    int nn = t >> 4;
    int c = t & 15;
    int node = n0 + nn;
    if (node >= N_NODES) { return; }
    const float* yr = Ys + nn * 132;
    float acc = 0.f;
    #pragma unroll 4
    for (int k = 0; k < 128; k++) {
        acc = fmaf(yr[k], Ws[k * 16 + c], acc);
    }
    out[(size_t)node * 16 + c] = acc + bg2[c];
}

// ---------------- gather SpMM, 16 channels (4x ILP) ----------------
__global__ __launch_bounds__(256) void gather16(const int* __restrict__ cnt,
                                                const int* __restrict__ nbr,
                                                const float* __restrict__ wgt,
                                                const float* __restrict__ T,
                                                float* __restrict__ Y) {
    int node = blockIdx.x * 16 + (threadIdx.x >> 4);
    int c = threadIdx.x & 15;
    if (node >= N_NODES) { return; }
    int n = cnt[node];
    if (n > CAP) { n = CAP; }
    const int* nb = nbr + (size_t)node * CAP;
    const float* wg = wgt + (size_t)node * CAP;
    float a0 = 0.f, a1 = 0.f, a2 = 0.f, a3 = 0.f;
    int k = 0;
    for (; k + 4 <= n; k += 4) {
        int4 j = *(const int4*)(nb + k);
        float4 w = *(const float4*)(wg + k);
        float t0 = T[(size_t)j.x * 16 + c];
        float t1 = T[(size_t)j.y * 16 + c];
        float t2 = T[(size_t)j.z * 16 + c];
        float t3 = T[(size_t)j.w * 16 + c];
        a0 = fmaf(w.x, t0, a0);
        a1 = fmaf(w.y, t1, a1);
        a2 = fmaf(w.z, t2, a2);
        a3 = fmaf(w.w, t3, a3);
    }
    for (; k < n; k++) { a0 = fmaf(wg[k], T[(size_t)nb[k] * 16 + c], a0); }
    Y[(size_t)node * 16 + c] = (a0 + a1) + (a2 + a3);
}

extern "C" void kernel_launch(void* const* d_in, const int* in_sizes, int n_in,
                              void* d_out, int out_size, void* d_ws, size_t ws_size,
                              hipStream_t stream) {
    const float* features = (const float*)d_in[0];
    const float* x   = (const float*)d_in[1];
    const float* W1  = (const float*)d_in[2];
    const float* W2  = (const float*)d_in[3];
    const float* Wg1 = (const float*)d_in[4];
    const float* bg1 = (const float*)d_in[5];
    const float* Wg2 = (const float*)d_in[6];
    const float* bg2 = (const float*)d_in[7];

    float* ws = (float*)d_ws;
    // region A [0, 2.56M) floats: fsp -> hbuf -> tmax -> xsp
    // region B [2.56M, 5.12M) floats: h1sp -> Hhi/Hlo -> t1 | y1
    float* hbuf = ws;
    float* tmax = ws;                          // 800,000 f (10000 x 80), over dead hbuf
    float* tv   = ws + 5120000;               // 300,000 f
    int*   ti   = (int*)(ws + 5420000);       // 300,000 i
    float* deg  = ws + 5720000;               // 10,000 f
    float* dis  = ws + 5730000;               // 10,000 f
    float* t2   = ws + 5740000;               // 160,000 f (W-splits live here early)
    int*   cnt  = (int*)(ws + 5900000);       // 10,000 i
    float* t1   = ws + 2560000;               // Hhi region, after gemm_s dead
    float* y1   = ws + 3840000;               // Hlo region, after gemm_s dead

    _Float16* fsphi = (_Float16*)ws;
    _Float16* fsplo = fsphi + 2560000;
    _Float16* xsphi = (_Float16*)ws;                    // after tmax dead (post topk)
    _Float16* xsplo = xsphi + 2560000;
    _Float16* h1hi = (_Float16*)(ws + 2560000);
    _Float16* h1lo = h1hi + 2560000;
    _Float16* Hhi  = (_Float16*)(ws + 2560000);
    _Float16* Hlo  = Hhi + 2560000;
    _Float16* W1thi = (_Float16*)(ws + 5740000);        // 65,536 halves each
    _Float16* W1tlo = W1thi + 65536;
    _Float16* W2thi = W1thi + 131072;
    _Float16* W2tlo = W1thi + 196608;
    _Float16* Wg1thi = (_Float16*)(ws + 5740000);       // reuse after MLP chain (128x256)
    _Float16* Wg1tlo = Wg1thi + 32768;

    float* out_f = (float*)d_out;             // 160,000 f32
    float* Adj   = out_f + 160000;            // 1e8 f32 = 400 MB
    float* Sbuf  = Adj;                       // S until topk (topk zeroes it)

    // CSR placement: workspace if it fits, else alias Adj (zero+scatter at end)
    size_t csr_off = 5910000;                                  // floats
    size_t csr_need = (csr_off + (size_t)N_NODES * CAP * 2) * sizeof(float);
    bool csr_in_ws = ws_size >= csr_need;
    int*   nbr = csr_in_ws ? (int*)(ws + csr_off) : (int*)Adj;
    float* wgt = csr_in_ws ? (float*)(ws + csr_off + (size_t)N_NODES * CAP)
                           : (float*)(Adj + (size_t)N_NODES * CAP);

    // ---- MLP chain via fp16-split MFMA ----
    split_rows<<<dim3(10000), dim3(256), 0, stream>>>(features, fsphi, fsplo, 2560000);
    splitWT<<<dim3(256), dim3(256), 0, stream>>>(W1, W1thi, W1tlo, 256);
    splitWT<<<dim3(256), dim3(256), 0, stream>>>(W2, W2thi, W2tlo, 256);
    gemm_mlp<1><<<dim3(2, 79), dim3(256), 0, stream>>>(
        fsphi, fsplo, W1thi, W1tlo, h1hi, h1lo, (float*)nullptr, (const float*)nullptr, 256);
    gemm_mlp<0><<<dim3(2, 79), dim3(256), 0, stream>>>(
        h1hi, h1lo, W2thi, W2tlo, (_Float16*)nullptr, (_Float16*)nullptr, hbuf,
        (const float*)nullptr, 256);
    rownorm_np_kernel<<<dim3(N_NODES), dim3(256), 0, stream>>>(hbuf, Hhi, Hlo);

    // ---- Wg1 split (W1t/W2t dead) ----
    splitWT<<<dim3(128), dim3(256), 0, stream>>>(Wg1, Wg1thi, Wg1tlo, 128);

    // ---- S (triangle + mirror) + tile maxes; pruned exact top-30 + zero + degrees ----
    gemm_s_f16<<<dim3(79, 79), dim3(256), 0, stream>>>(Hhi, Hlo, Sbuf, tmax);
    hipMemsetAsync(deg, 0, N_NODES * sizeof(float), stream);
    topk_sel_kernel<<<dim3(N_NODES), dim3(256), 0, stream>>>(Sbuf, tmax, tv, ti, deg);

    // ---- x split (tmax dead) + GCN layer-1 GEMM ----
    split_rows<<<dim3(10000), dim3(256), 0, stream>>>(x, xsphi, xsplo, 2560000);
    gemm_mlp<0><<<dim3(1, 79), dim3(256), 0, stream>>>(
        xsphi, xsplo, Wg1thi, Wg1tlo, (_Float16*)nullptr, (_Float16*)nullptr, t1, bg1, 128);

    dis_kernel<<<dim3((N_NODES + 255) / 256), dim3(256), 0, stream>>>(deg, dis);

    // ---- CSR build (+ fused Adj scatter when CSR lives in ws; S already zeroed) ----
    hipMemsetAsync(cnt, 0, N_NODES * sizeof(int), stream);
    int eblocks = (N_NODES * KTOP + 255) / 256;
    if (csr_in_ws) {
        csr_adj<1><<<dim3(eblocks), dim3(256), 0, stream>>>(tv, ti, dis, cnt, nbr, wgt, Adj);
    } else {
        csr_adj<0><<<dim3(eblocks), dim3(256), 0, stream>>>(tv, ti, dis, cnt, nbr, wgt, Adj);
    }

    // ---- GCN layers via gather SpMM ----
    gather128<<<dim3(N_NODES / 2), dim3(256), 0, stream>>>(cnt, nbr, wgt, t1, y1);
    gemm16<<<dim3(625), dim3(256), 0, stream>>>(y1, Wg2, bg2, t2);
    gather16<<<dim3((N_NODES + 15) / 16), dim3(256), 0, stream>>>(cnt, nbr, wgt, t2, out_f);

    // ---- fallback: CSR aliased Adj -> zero full Adj and scatter dense ----
    if (!csr_in_ws) {
        zero_fill<<<dim3(2048), dim3(256), 0, stream>>>(
            (float4*)Adj, (unsigned int)((size_t)N_NODES * N_NODES / 4));
        adj_scatter<<<dim3(eblocks), dim3(256), 0, stream>>>(tv, ti, dis, Adj);
    }
}